// Round 1
// baseline (1297.094 us; speedup 1.0000x reference)
//
#include <hip/hip_runtime.h>

#define NB 8
#define CIN 512
#define OIN 256
#define HWN 9216
#define KP 110
#define SCL 0.10206207261596577f  // 9216^(-0.25)

// ---------------------------------------------------------------------------
// Kernel 1: fused conv1x1 for phi and theta, with relu, per-batch GEMM
//   out[o, hw] = relu( sum_c W[o,c] * x[b,c,hw] + bias[o] )
//   o in [0,512): 0-255 -> phi buffer, 256-511 -> theta buffer
// Tiling: BM=64 (o), BN=128 (hw), BK=16. 256 threads, each 4x8 outputs.
// ---------------------------------------------------------------------------
__global__ __launch_bounds__(256) void conv_pt_kernel(
    const float* __restrict__ x,
    const float* __restrict__ phi_w, const float* __restrict__ phi_b,
    const float* __restrict__ theta_w, const float* __restrict__ theta_b,
    float* __restrict__ phi_out, float* __restrict__ theta_out)
{
    __shared__ float xs[16][128];
    __shared__ float wsT[16][64];

    const int b = blockIdx.z;
    const int o0 = blockIdx.y * 64;
    const int hw0 = blockIdx.x * 128;
    const int t = threadIdx.x;
    const int tx = t & 15, ty = t >> 4;

    const bool isPhi = (o0 < 256);
    const float* Wsel = isPhi ? phi_w : theta_w;
    const float* bsel = isPhi ? phi_b : theta_b;
    float* osel = isPhi ? phi_out : theta_out;
    const int oo0 = o0 & 255;

    const float* xb = x + (size_t)b * (CIN * HWN);

    float acc[4][8];
#pragma unroll
    for (int i = 0; i < 4; ++i)
#pragma unroll
        for (int j = 0; j < 8; ++j) acc[i][j] = 0.f;

    const int wo = t >> 2;         // 0..63  (local o for weight staging)
    const int wk = (t & 3) << 2;   // 0,4,8,12
    const float* wrow = Wsel + (size_t)(oo0 + wo) * CIN + wk;

    for (int kt = 0; kt < CIN; kt += 16) {
        // stage x tile [16][128] : 512 float4, 2 per thread
        {
            int i0 = t;
            int r = i0 >> 5, c = (i0 & 31) << 2;
            *(float4*)&xs[r][c] = *(const float4*)&xb[(size_t)(kt + r) * HWN + hw0 + c];
            int i1 = t + 256;
            r = i1 >> 5; c = (i1 & 31) << 2;
            *(float4*)&xs[r][c] = *(const float4*)&xb[(size_t)(kt + r) * HWN + hw0 + c];
        }
        // stage weight tile transposed: wsT[k][o]
        {
            float4 w = *(const float4*)&wrow[kt];
            wsT[wk + 0][wo] = w.x;
            wsT[wk + 1][wo] = w.y;
            wsT[wk + 2][wo] = w.z;
            wsT[wk + 3][wo] = w.w;
        }
        __syncthreads();
#pragma unroll
        for (int kk = 0; kk < 16; ++kk) {
            float4 a  = *(float4*)&wsT[kk][ty * 4];
            float4 b0 = *(float4*)&xs[kk][tx * 4];
            float4 b1 = *(float4*)&xs[kk][tx * 4 + 64];
            float av[4] = {a.x, a.y, a.z, a.w};
            float bv[8] = {b0.x, b0.y, b0.z, b0.w, b1.x, b1.y, b1.z, b1.w};
#pragma unroll
            for (int i = 0; i < 4; ++i)
#pragma unroll
                for (int j = 0; j < 8; ++j)
                    acc[i][j] = fmaf(av[i], bv[j], acc[i][j]);
        }
        __syncthreads();
    }

#pragma unroll
    for (int i = 0; i < 4; ++i) {
        int oo = oo0 + ty * 4 + i;
        float bias = bsel[oo];
        float* orow = osel + ((size_t)b * OIN + oo) * HWN + hw0;
        float4 v0, v1;
        v0.x = fmaxf(acc[i][0] + bias, 0.f);
        v0.y = fmaxf(acc[i][1] + bias, 0.f);
        v0.z = fmaxf(acc[i][2] + bias, 0.f);
        v0.w = fmaxf(acc[i][3] + bias, 0.f);
        v1.x = fmaxf(acc[i][4] + bias, 0.f);
        v1.y = fmaxf(acc[i][5] + bias, 0.f);
        v1.z = fmaxf(acc[i][6] + bias, 0.f);
        v1.w = fmaxf(acc[i][7] + bias, 0.f);
        *(float4*)&orow[tx * 4] = v0;
        *(float4*)&orow[tx * 4 + 64] = v1;
    }
}

// ---------------------------------------------------------------------------
// Kernel 2: SPP pooling of one [96][96] plane -> 110 means (scales 1,3,6,8)
// Stage A: 24x24 grid of 4x4-block sums in LDS; Stage B: 110 bins from those.
// ---------------------------------------------------------------------------
__global__ __launch_bounds__(256) void pool_kernel(
    const float* __restrict__ in, float* __restrict__ out)
{
    __shared__ float ps[576];
    const int plane = blockIdx.x;
    const float* p = in + (size_t)plane * HWN;
    const int t = threadIdx.x;

    for (int i = t; i < 576; i += 256) {
        int bh = i / 24, bw = i % 24;
        float s = 0.f;
#pragma unroll
        for (int r = 0; r < 4; ++r) {
            float4 v = *(const float4*)&p[(bh * 4 + r) * 96 + bw * 4];
            s += v.x + v.y + v.z + v.w;
        }
        ps[i] = s;
    }
    __syncthreads();

    if (t < KP) {
        float s = 0.f;
        if (t == 0) {
            for (int i = 0; i < 576; ++i) s += ps[i];
            s *= (1.0f / 9216.0f);
        } else if (t < 10) {
            int idx = t - 1, bi = idx / 3, bj = idx % 3;
            for (int r = 0; r < 8; ++r)
                for (int c = 0; c < 8; ++c)
                    s += ps[(bi * 8 + r) * 24 + bj * 8 + c];
            s *= (1.0f / 1024.0f);
        } else if (t < 46) {
            int idx = t - 10, bi = idx / 6, bj = idx % 6;
            for (int r = 0; r < 4; ++r)
                for (int c = 0; c < 4; ++c)
                    s += ps[(bi * 4 + r) * 24 + bj * 4 + c];
            s *= (1.0f / 256.0f);
        } else {
            int idx = t - 46, bi = idx / 8, bj = idx % 8;
            for (int r = 0; r < 3; ++r)
                for (int c = 0; c < 3; ++c)
                    s += ps[(bi * 3 + r) * 24 + bj * 3 + c];
            s *= (1.0f / 144.0f);
        }
        out[(size_t)plane * KP + t] = s;
    }
}

// ---------------------------------------------------------------------------
// Kernel 3: gamma_p transposed: gpt[b][k][o] = gamma_b[o] + sum_c gw[o,c]*xp[b,c,k]
// (pooling commutes with the linear gamma conv)
// grid (110, B), 256 threads = o
// ---------------------------------------------------------------------------
__global__ __launch_bounds__(256) void gammap_kernel(
    const float* __restrict__ xp,   // [B][512][110]
    const float* __restrict__ gw,   // [256][512]
    const float* __restrict__ gb,   // [256]
    float* __restrict__ gpt)        // [B][110][256]
{
    __shared__ float xc[512];
    const int k = blockIdx.x, b = blockIdx.y;
    const int t = threadIdx.x;

    xc[t]       = xp[((size_t)b * CIN + t) * KP + k];
    xc[t + 256] = xp[((size_t)b * CIN + t + 256) * KP + k];
    __syncthreads();

    float acc = gb[t];
    const float* wrow = gw + (size_t)t * CIN;
#pragma unroll 4
    for (int c = 0; c < CIN; c += 4) {
        float4 w = *(const float4*)&wrow[c];
        acc = fmaf(w.x, xc[c], acc);
        acc = fmaf(w.y, xc[c + 1], acc);
        acc = fmaf(w.z, xc[c + 2], acc);
        acc = fmaf(w.w, xc[c + 3], acc);
    }
    gpt[((size_t)b * KP + k) * OIN + t] = acc;
}

// ---------------------------------------------------------------------------
// Kernel 4: attention. One wave per row n (4 waves/block).
//  logits[k] = SCL * sum_c phi_flat[b, n*256+c] * tp[b,c,k]   (lane = k)
//  p = softmax over 110
//  y2[c] = sum_k p[k] * gpt[b,k,c]                            (lane covers 4 c)
//  write directly in y2_r layout: y2r[b, n/36, (n%36)*256 + c]
// ---------------------------------------------------------------------------
__global__ __launch_bounds__(256) void attn_kernel(
    const float* __restrict__ phi,  // [B][256*9216] flat
    const float* __restrict__ tp,   // [B][256][110]
    const float* __restrict__ gpt,  // [B][110][256]
    float* __restrict__ y2r)        // [B][256][9216]
{
    __shared__ float phs[4][256];
    __shared__ float ps[4][128];

    const int t = threadIdx.x;
    const int wid = t >> 6, lane = t & 63;
    const int b = blockIdx.y;
    const int n = blockIdx.x * 4 + wid;

    // load phi row (256 consecutive floats)
    const float* prow = phi + (size_t)b * (OIN * HWN) + (size_t)n * 256;
    *(float4*)&phs[wid][lane * 4] = *(const float4*)&prow[lane * 4];
    __syncthreads();

    // logits: lane holds k=lane and k=lane+64 (latter valid for lane<46)
    const float* tpb = tp + (size_t)b * OIN * KP;
    float acc1 = 0.f, acc2 = 0.f;
#pragma unroll 4
    for (int c = 0; c < 256; ++c) {
        float pc = phs[wid][c];
        const float* r = tpb + c * KP;
        acc1 = fmaf(pc, r[lane], acc1);
        acc2 = fmaf(pc, r[lane + 64], acc2);  // reads stray into next row; masked below
    }
    float l1 = acc1 * SCL;
    float l2 = acc2 * SCL;

    float m = fmaxf(l1, (lane < 46) ? l2 : -1e30f);
#pragma unroll
    for (int off = 32; off; off >>= 1) m = fmaxf(m, __shfl_xor(m, off, 64));
    float e1 = __expf(l1 - m);
    float e2 = (lane < 46) ? __expf(l2 - m) : 0.f;
    float ssum = e1 + e2;
#pragma unroll
    for (int off = 32; off; off >>= 1) ssum += __shfl_xor(ssum, off, 64);
    float inv = 1.0f / ssum;
    ps[wid][lane] = e1 * inv;
    ps[wid][lane + 64] = e2 * inv;
    __syncthreads();

    // y2: lane computes c = lane*4 .. lane*4+3
    const float* gb_ = gpt + (size_t)b * KP * OIN;
    float4 y = {0.f, 0.f, 0.f, 0.f};
#pragma unroll 2
    for (int k = 0; k < KP; ++k) {
        float pk = ps[wid][k];
        float4 g = *(const float4*)&gb_[k * OIN + lane * 4];
        y.x = fmaf(pk, g.x, y.x);
        y.y = fmaf(pk, g.y, y.y);
        y.z = fmaf(pk, g.z, y.z);
        y.w = fmaf(pk, g.w, y.w);
    }
    const int ci = n / 36, rr = n % 36;
    *(float4*)&y2r[((size_t)b * OIN + ci) * HWN + rr * 256 + lane * 4] = y;
}

// ---------------------------------------------------------------------------
// Kernel 5: final conv1x1 [512x256]x[256x9216] + bias + residual x
// ---------------------------------------------------------------------------
__global__ __launch_bounds__(256) void convw_kernel(
    const float* __restrict__ y2r,  // [B][256][9216]
    const float* __restrict__ Ww,   // [512][256]
    const float* __restrict__ Wb,   // [512]
    const float* __restrict__ x,    // [B][512][9216]
    float* __restrict__ out)        // [B][512][9216]
{
    __shared__ float xs[16][128];
    __shared__ float wsT[16][64];

    const int b = blockIdx.z;
    const int o0 = blockIdx.y * 64;
    const int hw0 = blockIdx.x * 128;
    const int t = threadIdx.x;
    const int tx = t & 15, ty = t >> 4;

    const float* yb = y2r + (size_t)b * (OIN * HWN);

    float acc[4][8];
#pragma unroll
    for (int i = 0; i < 4; ++i)
#pragma unroll
        for (int j = 0; j < 8; ++j) acc[i][j] = 0.f;

    const int wo = t >> 2;
    const int wk = (t & 3) << 2;
    const float* wrow = Ww + (size_t)(o0 + wo) * OIN + wk;

    for (int kt = 0; kt < OIN; kt += 16) {
        {
            int i0 = t;
            int r = i0 >> 5, c = (i0 & 31) << 2;
            *(float4*)&xs[r][c] = *(const float4*)&yb[(size_t)(kt + r) * HWN + hw0 + c];
            int i1 = t + 256;
            r = i1 >> 5; c = (i1 & 31) << 2;
            *(float4*)&xs[r][c] = *(const float4*)&yb[(size_t)(kt + r) * HWN + hw0 + c];
        }
        {
            float4 w = *(const float4*)&wrow[kt];
            wsT[wk + 0][wo] = w.x;
            wsT[wk + 1][wo] = w.y;
            wsT[wk + 2][wo] = w.z;
            wsT[wk + 3][wo] = w.w;
        }
        __syncthreads();
#pragma unroll
        for (int kk = 0; kk < 16; ++kk) {
            float4 a  = *(float4*)&wsT[kk][ty * 4];
            float4 b0 = *(float4*)&xs[kk][tx * 4];
            float4 b1 = *(float4*)&xs[kk][tx * 4 + 64];
            float av[4] = {a.x, a.y, a.z, a.w};
            float bv[8] = {b0.x, b0.y, b0.z, b0.w, b1.x, b1.y, b1.z, b1.w};
#pragma unroll
            for (int i = 0; i < 4; ++i)
#pragma unroll
                for (int j = 0; j < 8; ++j)
                    acc[i][j] = fmaf(av[i], bv[j], acc[i][j]);
        }
        __syncthreads();
    }

#pragma unroll
    for (int i = 0; i < 4; ++i) {
        int o = o0 + ty * 4 + i;
        float bias = Wb[o];
        const float* xrow = x + ((size_t)b * CIN + o) * HWN + hw0;
        float* orow = out + ((size_t)b * CIN + o) * HWN + hw0;
        float4 x0 = *(const float4*)&xrow[tx * 4];
        float4 x1 = *(const float4*)&xrow[tx * 4 + 64];
        float4 v0, v1;
        v0.x = acc[i][0] + bias + x0.x;
        v0.y = acc[i][1] + bias + x0.y;
        v0.z = acc[i][2] + bias + x0.z;
        v0.w = acc[i][3] + bias + x0.w;
        v1.x = acc[i][4] + bias + x1.x;
        v1.y = acc[i][5] + bias + x1.y;
        v1.z = acc[i][6] + bias + x1.z;
        v1.w = acc[i][7] + bias + x1.w;
        *(float4*)&orow[tx * 4] = v0;
        *(float4*)&orow[tx * 4 + 64] = v1;
    }
}

extern "C" void kernel_launch(void* const* d_in, const int* in_sizes, int n_in,
                              void* d_out, int out_size, void* d_ws, size_t ws_size,
                              hipStream_t stream)
{
    const float* x       = (const float*)d_in[0];
    const float* phi_w   = (const float*)d_in[1];
    const float* phi_b   = (const float*)d_in[2];
    const float* theta_w = (const float*)d_in[3];
    const float* theta_b = (const float*)d_in[4];
    const float* gamma_w = (const float*)d_in[5];
    const float* gamma_b = (const float*)d_in[6];
    const float* W_w     = (const float*)d_in[7];
    const float* W_b     = (const float*)d_in[8];
    float* out = (float*)d_out;

    char* ws = (char*)d_ws;
    const size_t SZP = (size_t)NB * OIN * HWN * sizeof(float);   // 75.5 MB
    float* phi  = (float*)(ws);
    float* buf2 = (float*)(ws + SZP);                            // theta_relu, later y2_r
    float* xp   = (float*)(ws + 2 * SZP);                        // [B][512][110]
    float* tp   = (float*)(ws + 2 * SZP + (size_t)NB * CIN * KP * 4);  // [B][256][110]
    float* gpt  = (float*)(ws + 2 * SZP + (size_t)NB * CIN * KP * 4
                                        + (size_t)NB * OIN * KP * 4);  // [B][110][256]

    conv_pt_kernel<<<dim3(72, 8, NB), 256, 0, stream>>>(x, phi_w, phi_b, theta_w, theta_b, phi, buf2);
    pool_kernel<<<dim3(NB * CIN), 256, 0, stream>>>(x, xp);
    pool_kernel<<<dim3(NB * OIN), 256, 0, stream>>>(buf2, tp);
    gammap_kernel<<<dim3(KP, NB), 256, 0, stream>>>(xp, gamma_w, gamma_b, gpt);
    attn_kernel<<<dim3(HWN / 4, NB), 256, 0, stream>>>(phi, tp, gpt, buf2);
    convw_kernel<<<dim3(72, 8, NB), 256, 0, stream>>>(buf2, W_w, W_b, x, out);
}

// Round 2
// 1050.891 us; speedup vs baseline: 1.2343x; 1.2343x over previous
//
#include <hip/hip_runtime.h>

#define NB 8
#define CIN 512
#define OIN 256
#define HWN 9216
#define KP 110
#define SCL 0.10206207261596577f  // 9216^(-0.25)

// ---------------------------------------------------------------------------
// Kernel 1: fused conv1x1 for phi and theta, with relu, per-batch GEMM
// ---------------------------------------------------------------------------
__global__ __launch_bounds__(256) void conv_pt_kernel(
    const float* __restrict__ x,
    const float* __restrict__ phi_w, const float* __restrict__ phi_b,
    const float* __restrict__ theta_w, const float* __restrict__ theta_b,
    float* __restrict__ phi_out, float* __restrict__ theta_out)
{
    __shared__ float xs[16][128];
    __shared__ float wsT[16][64];

    const int b = blockIdx.z;
    const int o0 = blockIdx.y * 64;
    const int hw0 = blockIdx.x * 128;
    const int t = threadIdx.x;
    const int tx = t & 15, ty = t >> 4;

    const bool isPhi = (o0 < 256);
    const float* Wsel = isPhi ? phi_w : theta_w;
    const float* bsel = isPhi ? phi_b : theta_b;
    float* osel = isPhi ? phi_out : theta_out;
    const int oo0 = o0 & 255;

    const float* xb = x + (size_t)b * (CIN * HWN);

    float acc[4][8];
#pragma unroll
    for (int i = 0; i < 4; ++i)
#pragma unroll
        for (int j = 0; j < 8; ++j) acc[i][j] = 0.f;

    const int wo = t >> 2;
    const int wk = (t & 3) << 2;
    const float* wrow = Wsel + (size_t)(oo0 + wo) * CIN + wk;

    for (int kt = 0; kt < CIN; kt += 16) {
        {
            int i0 = t;
            int r = i0 >> 5, c = (i0 & 31) << 2;
            *(float4*)&xs[r][c] = *(const float4*)&xb[(size_t)(kt + r) * HWN + hw0 + c];
            int i1 = t + 256;
            r = i1 >> 5; c = (i1 & 31) << 2;
            *(float4*)&xs[r][c] = *(const float4*)&xb[(size_t)(kt + r) * HWN + hw0 + c];
        }
        {
            float4 w = *(const float4*)&wrow[kt];
            wsT[wk + 0][wo] = w.x;
            wsT[wk + 1][wo] = w.y;
            wsT[wk + 2][wo] = w.z;
            wsT[wk + 3][wo] = w.w;
        }
        __syncthreads();
#pragma unroll
        for (int kk = 0; kk < 16; ++kk) {
            float4 a  = *(float4*)&wsT[kk][ty * 4];
            float4 b0 = *(float4*)&xs[kk][tx * 4];
            float4 b1 = *(float4*)&xs[kk][tx * 4 + 64];
            float av[4] = {a.x, a.y, a.z, a.w};
            float bv[8] = {b0.x, b0.y, b0.z, b0.w, b1.x, b1.y, b1.z, b1.w};
#pragma unroll
            for (int i = 0; i < 4; ++i)
#pragma unroll
                for (int j = 0; j < 8; ++j)
                    acc[i][j] = fmaf(av[i], bv[j], acc[i][j]);
        }
        __syncthreads();
    }

#pragma unroll
    for (int i = 0; i < 4; ++i) {
        int oo = oo0 + ty * 4 + i;
        float bias = bsel[oo];
        float* orow = osel + ((size_t)b * OIN + oo) * HWN + hw0;
        float4 v0, v1;
        v0.x = fmaxf(acc[i][0] + bias, 0.f);
        v0.y = fmaxf(acc[i][1] + bias, 0.f);
        v0.z = fmaxf(acc[i][2] + bias, 0.f);
        v0.w = fmaxf(acc[i][3] + bias, 0.f);
        v1.x = fmaxf(acc[i][4] + bias, 0.f);
        v1.y = fmaxf(acc[i][5] + bias, 0.f);
        v1.z = fmaxf(acc[i][6] + bias, 0.f);
        v1.w = fmaxf(acc[i][7] + bias, 0.f);
        *(float4*)&orow[tx * 4] = v0;
        *(float4*)&orow[tx * 4 + 64] = v1;
    }
}

// ---------------------------------------------------------------------------
// Kernel 2: SPP pooling of one [96][96] plane -> 110 means
// ---------------------------------------------------------------------------
__global__ __launch_bounds__(256) void pool_kernel(
    const float* __restrict__ in, float* __restrict__ out)
{
    __shared__ float ps[576];
    const int plane = blockIdx.x;
    const float* p = in + (size_t)plane * HWN;
    const int t = threadIdx.x;

    for (int i = t; i < 576; i += 256) {
        int bh = i / 24, bw = i % 24;
        float s = 0.f;
#pragma unroll
        for (int r = 0; r < 4; ++r) {
            float4 v = *(const float4*)&p[(bh * 4 + r) * 96 + bw * 4];
            s += v.x + v.y + v.z + v.w;
        }
        ps[i] = s;
    }
    __syncthreads();

    if (t < KP) {
        float s = 0.f;
        if (t == 0) {
            for (int i = 0; i < 576; ++i) s += ps[i];
            s *= (1.0f / 9216.0f);
        } else if (t < 10) {
            int idx = t - 1, bi = idx / 3, bj = idx % 3;
            for (int r = 0; r < 8; ++r)
                for (int c = 0; c < 8; ++c)
                    s += ps[(bi * 8 + r) * 24 + bj * 8 + c];
            s *= (1.0f / 1024.0f);
        } else if (t < 46) {
            int idx = t - 10, bi = idx / 6, bj = idx % 6;
            for (int r = 0; r < 4; ++r)
                for (int c = 0; c < 4; ++c)
                    s += ps[(bi * 4 + r) * 24 + bj * 4 + c];
            s *= (1.0f / 256.0f);
        } else {
            int idx = t - 46, bi = idx / 8, bj = idx % 8;
            for (int r = 0; r < 3; ++r)
                for (int c = 0; c < 3; ++c)
                    s += ps[(bi * 3 + r) * 24 + bj * 3 + c];
            s *= (1.0f / 144.0f);
        }
        out[(size_t)plane * KP + t] = s;
    }
}

// ---------------------------------------------------------------------------
// Kernel 3: gamma_p transposed: gpt[b][k][o]
// ---------------------------------------------------------------------------
__global__ __launch_bounds__(256) void gammap_kernel(
    const float* __restrict__ xp,   // [B][512][110]
    const float* __restrict__ gw,   // [256][512]
    const float* __restrict__ gb,   // [256]
    float* __restrict__ gpt)        // [B][110][256]
{
    __shared__ float xc[512];
    const int k = blockIdx.x, b = blockIdx.y;
    const int t = threadIdx.x;

    xc[t]       = xp[((size_t)b * CIN + t) * KP + k];
    xc[t + 256] = xp[((size_t)b * CIN + t + 256) * KP + k];
    __syncthreads();

    float acc = gb[t];
    const float* wrow = gw + (size_t)t * CIN;
#pragma unroll 4
    for (int c = 0; c < CIN; c += 4) {
        float4 w = *(const float4*)&wrow[c];
        acc = fmaf(w.x, xc[c], acc);
        acc = fmaf(w.y, xc[c + 1], acc);
        acc = fmaf(w.z, xc[c + 2], acc);
        acc = fmaf(w.w, xc[c + 3], acc);
    }
    gpt[((size_t)b * KP + k) * OIN + t] = acc;
}

// ---------------------------------------------------------------------------
// Kernel 4: fused attention, tiled. Block = 128 rows of one batch.
//  GEMM1: L[128][128p] = phi_rows[128][256] x tp[256][110pad]  (LDS-staged)
//  softmax in registers (shfl_xor over 16-lane row groups)
//  P -> LDS [128][113] (K padded to 112 with zeros)
//  GEMM2: y2[128][256] = P[128][112] x gpt[112pad][256], gpt LDS-chunked
//  write directly in y2_r layout.
// ---------------------------------------------------------------------------
__global__ __launch_bounds__(256) void attn_kernel(
    const float* __restrict__ phi,  // [B][256*9216] flat
    const float* __restrict__ tp,   // [B][256][110]
    const float* __restrict__ gpt,  // [B][110][256]
    float* __restrict__ y2r)        // [B][256][9216]
{
    __shared__ __align__(16) char smem[61952];
    float (*As)[128] = (float (*)[128])smem;             // [16][128] phase 1
    float (*Bs)[128] = (float (*)[128])(smem + 8192);    // [16][128] phase 1
    float (*Ps)[113] = (float (*)[113])smem;             // [128][113] phase 2
    float (*Gs)[128] = (float (*)[128])(smem + 57856);   // [8][128]  phase 2

    const int t = threadIdx.x;
    const int tx = t & 15, ty = t >> 4;
    const int b = blockIdx.y;
    const int m0 = blockIdx.x * 128;

    const float* phib = phi + (size_t)b * (OIN * HWN);
    const float* tpb  = tp  + (size_t)b * (OIN * KP);
    const float* gptb = gpt + (size_t)b * (KP * OIN);
    float* y2rb = y2r + (size_t)b * (OIN * HWN);

    float acc[8][8];
#pragma unroll
    for (int i = 0; i < 8; ++i)
#pragma unroll
        for (int j = 0; j < 8; ++j) acc[i][j] = 0.f;

    // staging maps
    const int am = t >> 1, ac = (t & 1) * 8;                // A: 128 rows x 16 k
    const float* arow = phib + (size_t)(m0 + am) * 256 + ac;
    const int br = ty, bn0 = tx * 8;                        // B: 16 k x 128 n

    // ---------------- GEMM1: K=256 in steps of 16 ----------------
    for (int kt = 0; kt < 256; kt += 16) {
        float4 a0 = *(const float4*)(arow + kt);
        float4 a1 = *(const float4*)(arow + kt + 4);
        float bv[8];
#pragma unroll
        for (int j = 0; j < 8; ++j) {
            int n = bn0 + j;
            bv[j] = (n < KP) ? tpb[(size_t)(kt + br) * KP + n] : 0.f;
        }
        __syncthreads();
        As[ac + 0][am] = a0.x; As[ac + 1][am] = a0.y;
        As[ac + 2][am] = a0.z; As[ac + 3][am] = a0.w;
        As[ac + 4][am] = a1.x; As[ac + 5][am] = a1.y;
        As[ac + 6][am] = a1.z; As[ac + 7][am] = a1.w;
#pragma unroll
        for (int j = 0; j < 8; ++j) Bs[br][bn0 + j] = bv[j];
        __syncthreads();
#pragma unroll
        for (int kk = 0; kk < 16; ++kk) {
            float4 x0 = *(float4*)&As[kk][ty * 8];
            float4 x1 = *(float4*)&As[kk][ty * 8 + 4];
            float4 y0 = *(float4*)&Bs[kk][tx * 8];
            float4 y1 = *(float4*)&Bs[kk][tx * 8 + 4];
            float av[8] = {x0.x, x0.y, x0.z, x0.w, x1.x, x1.y, x1.z, x1.w};
            float bvv[8] = {y0.x, y0.y, y0.z, y0.w, y1.x, y1.y, y1.z, y1.w};
#pragma unroll
            for (int i = 0; i < 8; ++i)
#pragma unroll
                for (int j = 0; j < 8; ++j)
                    acc[i][j] = fmaf(av[i], bvv[j], acc[i][j]);
        }
        __syncthreads();
    }

    // ---------------- softmax over n (110 valid) ----------------
#pragma unroll
    for (int i = 0; i < 8; ++i) {
        float mx = -1e30f;
#pragma unroll
        for (int j = 0; j < 8; ++j) {
            float l = acc[i][j] * SCL;
            acc[i][j] = l;
            if (bn0 + j < KP) mx = fmaxf(mx, l);
        }
        mx = fmaxf(mx, __shfl_xor(mx, 1));
        mx = fmaxf(mx, __shfl_xor(mx, 2));
        mx = fmaxf(mx, __shfl_xor(mx, 4));
        mx = fmaxf(mx, __shfl_xor(mx, 8));
        float s = 0.f;
#pragma unroll
        for (int j = 0; j < 8; ++j) {
            float e = (bn0 + j < KP) ? __expf(acc[i][j] - mx) : 0.f;
            acc[i][j] = e;
            s += e;
        }
        s += __shfl_xor(s, 1);
        s += __shfl_xor(s, 2);
        s += __shfl_xor(s, 4);
        s += __shfl_xor(s, 8);
        float inv = 1.0f / s;
#pragma unroll
        for (int j = 0; j < 8; ++j) acc[i][j] *= inv;
    }

    __syncthreads();  // all GEMM1 LDS reads done before Ps overwrites As/Bs
    if (tx < 14) {
#pragma unroll
        for (int i = 0; i < 8; ++i)
#pragma unroll
            for (int j = 0; j < 8; ++j)
                Ps[ty * 8 + i][tx * 8 + j] = acc[i][j];
    }

    // ---------------- GEMM2: [128 m][256 c] = P[128][112] x gpt ----------------
    const int gkr = t >> 5, gc = (t & 31) * 4;
#pragma unroll 1
    for (int ch = 0; ch < 2; ++ch) {
        const int cb = ch * 128;
        float acc2[8][8];
#pragma unroll
        for (int i = 0; i < 8; ++i)
#pragma unroll
            for (int j = 0; j < 8; ++j) acc2[i][j] = 0.f;

#pragma unroll 1
        for (int kc = 0; kc < 112; kc += 8) {
            float4 g = {0.f, 0.f, 0.f, 0.f};
            if (kc + gkr < KP)
                g = *(const float4*)&gptb[(size_t)(kc + gkr) * OIN + cb + gc];
            __syncthreads();
            *(float4*)&Gs[gkr][gc] = g;
            __syncthreads();
#pragma unroll
            for (int kk = 0; kk < 8; ++kk) {
                float pk[8];
#pragma unroll
                for (int i = 0; i < 8; ++i) pk[i] = Ps[ty * 8 + i][kc + kk];
                float4 g0 = *(float4*)&Gs[kk][tx * 8];
                float4 g1 = *(float4*)&Gs[kk][tx * 8 + 4];
                float gv[8] = {g0.x, g0.y, g0.z, g0.w, g1.x, g1.y, g1.z, g1.w};
#pragma unroll
                for (int i = 0; i < 8; ++i)
#pragma unroll
                    for (int j = 0; j < 8; ++j)
                        acc2[i][j] = fmaf(pk[i], gv[j], acc2[i][j]);
            }
        }

#pragma unroll
        for (int i = 0; i < 8; ++i) {
            int n = m0 + ty * 8 + i;
            int ci = n / 36, rr = n % 36;
            float* dst = y2rb + (size_t)ci * HWN + rr * 256 + cb + tx * 8;
            float4 v0 = {acc2[i][0], acc2[i][1], acc2[i][2], acc2[i][3]};
            float4 v1 = {acc2[i][4], acc2[i][5], acc2[i][6], acc2[i][7]};
            *(float4*)&dst[0] = v0;
            *(float4*)&dst[4] = v1;
        }
    }
}

// ---------------------------------------------------------------------------
// Kernel 5: final conv1x1 [512x256]x[256x9216] + bias + residual x
// ---------------------------------------------------------------------------
__global__ __launch_bounds__(256) void convw_kernel(
    const float* __restrict__ y2r,  // [B][256][9216]
    const float* __restrict__ Ww,   // [512][256]
    const float* __restrict__ Wb,   // [512]
    const float* __restrict__ x,    // [B][512][9216]
    float* __restrict__ out)        // [B][512][9216]
{
    __shared__ float xs[16][128];
    __shared__ float wsT[16][64];

    const int b = blockIdx.z;
    const int o0 = blockIdx.y * 64;
    const int hw0 = blockIdx.x * 128;
    const int t = threadIdx.x;
    const int tx = t & 15, ty = t >> 4;

    const float* yb = y2r + (size_t)b * (OIN * HWN);

    float acc[4][8];
#pragma unroll
    for (int i = 0; i < 4; ++i)
#pragma unroll
        for (int j = 0; j < 8; ++j) acc[i][j] = 0.f;

    const int wo = t >> 2;
    const int wk = (t & 3) << 2;
    const float* wrow = Ww + (size_t)(o0 + wo) * OIN + wk;

    for (int kt = 0; kt < OIN; kt += 16) {
        {
            int i0 = t;
            int r = i0 >> 5, c = (i0 & 31) << 2;
            *(float4*)&xs[r][c] = *(const float4*)&yb[(size_t)(kt + r) * HWN + hw0 + c];
            int i1 = t + 256;
            r = i1 >> 5; c = (i1 & 31) << 2;
            *(float4*)&xs[r][c] = *(const float4*)&yb[(size_t)(kt + r) * HWN + hw0 + c];
        }
        {
            float4 w = *(const float4*)&wrow[kt];
            wsT[wk + 0][wo] = w.x;
            wsT[wk + 1][wo] = w.y;
            wsT[wk + 2][wo] = w.z;
            wsT[wk + 3][wo] = w.w;
        }
        __syncthreads();
#pragma unroll
        for (int kk = 0; kk < 16; ++kk) {
            float4 a  = *(float4*)&wsT[kk][ty * 4];
            float4 b0 = *(float4*)&xs[kk][tx * 4];
            float4 b1 = *(float4*)&xs[kk][tx * 4 + 64];
            float av[4] = {a.x, a.y, a.z, a.w};
            float bv[8] = {b0.x, b0.y, b0.z, b0.w, b1.x, b1.y, b1.z, b1.w};
#pragma unroll
            for (int i = 0; i < 4; ++i)
#pragma unroll
                for (int j = 0; j < 8; ++j)
                    acc[i][j] = fmaf(av[i], bv[j], acc[i][j]);
        }
        __syncthreads();
    }

#pragma unroll
    for (int i = 0; i < 4; ++i) {
        int o = o0 + ty * 4 + i;
        float bias = Wb[o];
        const float* xrow = x + ((size_t)b * CIN + o) * HWN + hw0;
        float* orow = out + ((size_t)b * CIN + o) * HWN + hw0;
        float4 x0 = *(const float4*)&xrow[tx * 4];
        float4 x1 = *(const float4*)&xrow[tx * 4 + 64];
        float4 v0, v1;
        v0.x = acc[i][0] + bias + x0.x;
        v0.y = acc[i][1] + bias + x0.y;
        v0.z = acc[i][2] + bias + x0.z;
        v0.w = acc[i][3] + bias + x0.w;
        v1.x = acc[i][4] + bias + x1.x;
        v1.y = acc[i][5] + bias + x1.y;
        v1.z = acc[i][6] + bias + x1.z;
        v1.w = acc[i][7] + bias + x1.w;
        *(float4*)&orow[tx * 4] = v0;
        *(float4*)&orow[tx * 4 + 64] = v1;
    }
}

extern "C" void kernel_launch(void* const* d_in, const int* in_sizes, int n_in,
                              void* d_out, int out_size, void* d_ws, size_t ws_size,
                              hipStream_t stream)
{
    const float* x       = (const float*)d_in[0];
    const float* phi_w   = (const float*)d_in[1];
    const float* phi_b   = (const float*)d_in[2];
    const float* theta_w = (const float*)d_in[3];
    const float* theta_b = (const float*)d_in[4];
    const float* gamma_w = (const float*)d_in[5];
    const float* gamma_b = (const float*)d_in[6];
    const float* W_w     = (const float*)d_in[7];
    const float* W_b     = (const float*)d_in[8];
    float* out = (float*)d_out;

    char* ws = (char*)d_ws;
    const size_t SZP = (size_t)NB * OIN * HWN * sizeof(float);   // 75.5 MB
    float* phi  = (float*)(ws);
    float* buf2 = (float*)(ws + SZP);                            // theta_relu, later y2_r
    float* xp   = (float*)(ws + 2 * SZP);                        // [B][512][110]
    float* tp   = (float*)(ws + 2 * SZP + (size_t)NB * CIN * KP * 4);  // [B][256][110]
    float* gpt  = (float*)(ws + 2 * SZP + (size_t)NB * CIN * KP * 4
                                        + (size_t)NB * OIN * KP * 4);  // [B][110][256]

    conv_pt_kernel<<<dim3(72, 8, NB), 256, 0, stream>>>(x, phi_w, phi_b, theta_w, theta_b, phi, buf2);
    pool_kernel<<<dim3(NB * CIN), 256, 0, stream>>>(x, xp);
    pool_kernel<<<dim3(NB * OIN), 256, 0, stream>>>(buf2, tp);
    gammap_kernel<<<dim3(KP, NB), 256, 0, stream>>>(xp, gamma_w, gamma_b, gpt);
    attn_kernel<<<dim3(HWN / 128, NB), 256, 0, stream>>>(phi, tp, gpt, buf2);
    convw_kernel<<<dim3(72, 8, NB), 256, 0, stream>>>(buf2, W_w, W_b, x, out);
}

// Round 3
// 701.784 us; speedup vs baseline: 1.8483x; 1.4975x over previous
//
#include <hip/hip_runtime.h>

#define NB 8
#define CIN 512
#define OIN 256
#define HWN 9216
#define KP 110
#define SCL 0.10206207261596577f  // 9216^(-0.25)

typedef __attribute__((ext_vector_type(8))) short bf16x8;
typedef __attribute__((ext_vector_type(4))) float f32x4;

__device__ inline unsigned bf16_1(float a) {
    unsigned u = __builtin_bit_cast(unsigned, a);
    return (u + 0x7fffu + ((u >> 16) & 1u)) >> 16;
}
__device__ inline unsigned bf16_pack(float a, float b) {
    return bf16_1(a) | (bf16_1(b) << 16);
}
__device__ inline int swz(int r) { return (r & 7) ^ ((r >> 3) & 7); }

// ---------------------------------------------------------------------------
// Weight cast: phi_w+theta_w -> Wcat bf16 [512][512]; W_w -> Wwb bf16 [512][256]
// ---------------------------------------------------------------------------
__global__ __launch_bounds__(256) void castw_kernel(
    const float* __restrict__ phi_w, const float* __restrict__ theta_w,
    const float* __restrict__ Ww,
    unsigned short* __restrict__ Wcat, unsigned short* __restrict__ Wwb)
{
    int i = blockIdx.x * 256 + threadIdx.x;
    if (i < 262144) {
        float v = (i < 131072) ? phi_w[i] : theta_w[i - 131072];
        Wcat[i] = (unsigned short)bf16_1(v);
    } else {
        int j = i - 262144;
        Wwb[j] = (unsigned short)bf16_1(Ww[j]);
    }
}

// ---------------------------------------------------------------------------
// MFMA GEMM: D[m=hw][n=o] = sum_k Adata[k][m] * Bw[n][k]   (per batch)
//  Adata: [B][KDIM][9216] fp32 (x or y2r) — reg-staged + cast to bf16, LDS k-minor
//  Bw:    [512][KDIM] bf16 — reg-staged b128, LDS k-minor
//  Tile 128x128, BK=64, 4 waves, 4x4 16x16x32 frags per wave.
//  MODE 0 (conv_pt): +bias, relu, split n<256 -> out0(phi), n>=256 -> out1(theta)
//  MODE 1 (convw):   +bias, +resid(x), -> out0
// Output written transposed: dst[o][hw] (fp32), matching raw-reshape layouts.
// ---------------------------------------------------------------------------
template<int KDIM, int MODE>
__global__ __launch_bounds__(256) void gemm_kernel(
    const float* __restrict__ Adata,
    const unsigned short* __restrict__ Bw,
    const float* __restrict__ b0, const float* __restrict__ b1,
    const float* __restrict__ resid,
    float* __restrict__ out0, float* __restrict__ out1)
{
    __shared__ short As[128 * 64];   // [m][k] bf16, swizzled 16B slots
    __shared__ short Bs[128 * 64];   // [n][k] bf16, swizzled 16B slots

    const int t = threadIdx.x;
    const int b = blockIdx.z;
    const int m0 = blockIdx.x * 128;
    const int n0 = blockIdx.y * 128;
    const int w = t >> 6, l = t & 63;
    const int wr = w >> 1, wc = w & 1;           // wave sub-tile (wr*64, wc*64)
    const int fq = l >> 4;

    const float* Ab = Adata + (size_t)b * KDIM * HWN;

    f32x4 zero = {0.f, 0.f, 0.f, 0.f};
    f32x4 acc[4][4];
#pragma unroll
    for (int i = 0; i < 4; ++i)
#pragma unroll
        for (int j = 0; j < 4; ++j) acc[i][j] = zero;

    // A staging map: qa = col-chunk (16 floats), kp = k-pair
    const int qa = t & 7, kp = t >> 3;           // kp in [0,32)
    // B staging map: rb = row, 4 slots of 8 bf16
    const int rb = t >> 1, sb0 = (t & 1) * 4;

#pragma unroll 1
    for (int kt = 0; kt < KDIM; kt += 64) {
        // ---- global loads (before barrier: overlap prior compute) ----
        const float* r0 = Ab + (size_t)(kt + 2 * kp) * HWN + m0 + 16 * qa;
        const float* r1 = r0 + HWN;
        float4 a0[4], a1[4];
#pragma unroll
        for (int i = 0; i < 4; ++i) {
            a0[i] = *(const float4*)(r0 + 4 * i);
            a1[i] = *(const float4*)(r1 + 4 * i);
        }
        uint4 bv[4];
#pragma unroll
        for (int i = 0; i < 4; ++i)
            bv[i] = *(const uint4*)(Bw + (size_t)(n0 + rb) * KDIM + kt + (sb0 + i) * 8);

        __syncthreads();   // prior LDS reads done

        // ---- A: pack fp32 pairs -> bf16x2, transposed k-minor write ----
        {
            const float* f0 = (const float*)a0;
            const float* f1 = (const float*)a1;
#pragma unroll
            for (int j = 0; j < 16; ++j) {
                int r = 16 * qa + j;
                int byte = r * 128 + (((kp >> 2) ^ swz(r)) << 4) + ((kp & 3) << 2);
                *(unsigned*)((char*)As + byte) = bf16_pack(f0[j], f1[j]);
            }
        }
        // ---- B: b128 swizzled writes ----
#pragma unroll
        for (int i = 0; i < 4; ++i) {
            int s = sb0 + i;
            int byte = rb * 128 + ((s ^ swz(rb)) << 4);
            *(uint4*)((char*)Bs + byte) = bv[i];
        }
        __syncthreads();

        // ---- compute: 2 k-halves x 4x4 MFMA ----
#pragma unroll
        for (int h = 0; h < 2; ++h) {
            bf16x8 af[4], bfr[4];
#pragma unroll
            for (int mi = 0; mi < 4; ++mi) {
                int r = wr * 64 + mi * 16 + (l & 15);
                int byte = r * 128 + (((h * 4 + fq) ^ swz(r)) << 4);
                af[mi] = *(const bf16x8*)((const char*)As + byte);
            }
#pragma unroll
            for (int ni = 0; ni < 4; ++ni) {
                int r = wc * 64 + ni * 16 + (l & 15);
                int byte = r * 128 + (((h * 4 + fq) ^ swz(r)) << 4);
                bfr[ni] = *(const bf16x8*)((const char*)Bs + byte);
            }
#pragma unroll
            for (int mi = 0; mi < 4; ++mi)
#pragma unroll
                for (int ni = 0; ni < 4; ++ni)
                    acc[mi][ni] = __builtin_amdgcn_mfma_f32_16x16x32_bf16(
                        af[mi], bfr[ni], acc[mi][ni], 0, 0, 0);
        }
    }

    // ---- epilogue: transposed store D[m][n] -> dst[n][m] ----
#pragma unroll
    for (int ni = 0; ni < 4; ++ni) {
        int n = n0 + wc * 64 + ni * 16 + (l & 15);
        float bias;
        float* dst;
        const float* res = nullptr;
        if (MODE == 0) {
            if (n < 256) { bias = b0[n];       dst = out0 + ((size_t)b * 256 + n) * HWN; }
            else         { bias = b1[n - 256]; dst = out1 + ((size_t)b * 256 + (n - 256)) * HWN; }
        } else {
            bias = b0[n];
            dst = out0 + ((size_t)b * 512 + n) * HWN;
            res = resid + ((size_t)b * 512 + n) * HWN;
        }
#pragma unroll
        for (int mi = 0; mi < 4; ++mi) {
            int m = m0 + wr * 64 + mi * 16 + (fq << 2);
            f32x4 v = acc[mi][ni];
            float4 o;
            if (MODE == 0) {
                o.x = fmaxf(v.x + bias, 0.f);
                o.y = fmaxf(v.y + bias, 0.f);
                o.z = fmaxf(v.z + bias, 0.f);
                o.w = fmaxf(v.w + bias, 0.f);
            } else {
                float4 rx = *(const float4*)(res + m);
                o.x = v.x + bias + rx.x;
                o.y = v.y + bias + rx.y;
                o.z = v.z + bias + rx.z;
                o.w = v.w + bias + rx.w;
            }
            *(float4*)(dst + m) = o;
        }
    }
}

// ---------------------------------------------------------------------------
// SPP pooling of one [96][96] plane -> 110 means (scales 1,3,6,8)
// ---------------------------------------------------------------------------
__global__ __launch_bounds__(256) void pool_kernel(
    const float* __restrict__ in, float* __restrict__ out)
{
    __shared__ float ps[576];
    const int plane = blockIdx.x;
    const float* p = in + (size_t)plane * HWN;
    const int t = threadIdx.x;

    for (int i = t; i < 576; i += 256) {
        int bh = i / 24, bw = i % 24;
        float s = 0.f;
#pragma unroll
        for (int r = 0; r < 4; ++r) {
            float4 v = *(const float4*)&p[(bh * 4 + r) * 96 + bw * 4];
            s += v.x + v.y + v.z + v.w;
        }
        ps[i] = s;
    }
    __syncthreads();

    if (t < KP) {
        float s = 0.f;
        if (t == 0) {
            for (int i = 0; i < 576; ++i) s += ps[i];
            s *= (1.0f / 9216.0f);
        } else if (t < 10) {
            int idx = t - 1, bi = idx / 3, bj = idx % 3;
            for (int r = 0; r < 8; ++r)
                for (int c = 0; c < 8; ++c)
                    s += ps[(bi * 8 + r) * 24 + bj * 8 + c];
            s *= (1.0f / 1024.0f);
        } else if (t < 46) {
            int idx = t - 10, bi = idx / 6, bj = idx % 6;
            for (int r = 0; r < 4; ++r)
                for (int c = 0; c < 4; ++c)
                    s += ps[(bi * 4 + r) * 24 + bj * 4 + c];
            s *= (1.0f / 256.0f);
        } else {
            int idx = t - 46, bi = idx / 8, bj = idx % 8;
            for (int r = 0; r < 3; ++r)
                for (int c = 0; c < 3; ++c)
                    s += ps[(bi * 3 + r) * 24 + bj * 3 + c];
            s *= (1.0f / 144.0f);
        }
        out[(size_t)plane * KP + t] = s;
    }
}

// ---------------------------------------------------------------------------
// gamma_p transposed: gpt[b][k][o] (pooling commutes with the linear conv)
// ---------------------------------------------------------------------------
__global__ __launch_bounds__(256) void gammap_kernel(
    const float* __restrict__ xp,   // [B][512][110]
    const float* __restrict__ gw,   // [256][512]
    const float* __restrict__ gb,   // [256]
    float* __restrict__ gpt)        // [B][110][256]
{
    __shared__ float xc[512];
    const int k = blockIdx.x, b = blockIdx.y;
    const int t = threadIdx.x;

    xc[t]       = xp[((size_t)b * CIN + t) * KP + k];
    xc[t + 256] = xp[((size_t)b * CIN + t + 256) * KP + k];
    __syncthreads();

    float acc = gb[t];
    const float* wrow = gw + (size_t)t * CIN;
#pragma unroll 4
    for (int c = 0; c < CIN; c += 4) {
        float4 w = *(const float4*)&wrow[c];
        acc = fmaf(w.x, xc[c], acc);
        acc = fmaf(w.y, xc[c + 1], acc);
        acc = fmaf(w.z, xc[c + 2], acc);
        acc = fmaf(w.w, xc[c + 3], acc);
    }
    gpt[((size_t)b * KP + k) * OIN + t] = acc;
}

// ---------------------------------------------------------------------------
// Fused attention, tiled. Block = 128 rows of one batch. (round-2 version)
// ---------------------------------------------------------------------------
__global__ __launch_bounds__(256) void attn_kernel(
    const float* __restrict__ phi,  // [B][256*9216] flat
    const float* __restrict__ tp,   // [B][256][110]
    const float* __restrict__ gpt,  // [B][110][256]
    float* __restrict__ y2r)        // [B][256][9216]
{
    __shared__ __align__(16) char smem[61952];
    float (*As)[128] = (float (*)[128])smem;             // [16][128] phase 1
    float (*Bs)[128] = (float (*)[128])(smem + 8192);    // [16][128] phase 1
    float (*Ps)[113] = (float (*)[113])smem;             // [128][113] phase 2
    float (*Gs)[128] = (float (*)[128])(smem + 57856);   // [8][128]  phase 2

    const int t = threadIdx.x;
    const int tx = t & 15, ty = t >> 4;
    const int b = blockIdx.y;
    const int m0 = blockIdx.x * 128;

    const float* phib = phi + (size_t)b * (OIN * HWN);
    const float* tpb  = tp  + (size_t)b * (OIN * KP);
    const float* gptb = gpt + (size_t)b * (KP * OIN);
    float* y2rb = y2r + (size_t)b * (OIN * HWN);

    float acc[8][8];
#pragma unroll
    for (int i = 0; i < 8; ++i)
#pragma unroll
        for (int j = 0; j < 8; ++j) acc[i][j] = 0.f;

    const int am = t >> 1, ac = (t & 1) * 8;
    const float* arow = phib + (size_t)(m0 + am) * 256 + ac;
    const int br = ty, bn0 = tx * 8;

    for (int kt = 0; kt < 256; kt += 16) {
        float4 a0 = *(const float4*)(arow + kt);
        float4 a1 = *(const float4*)(arow + kt + 4);
        float bv[8];
#pragma unroll
        for (int j = 0; j < 8; ++j) {
            int n = bn0 + j;
            bv[j] = (n < KP) ? tpb[(size_t)(kt + br) * KP + n] : 0.f;
        }
        __syncthreads();
        As[ac + 0][am] = a0.x; As[ac + 1][am] = a0.y;
        As[ac + 2][am] = a0.z; As[ac + 3][am] = a0.w;
        As[ac + 4][am] = a1.x; As[ac + 5][am] = a1.y;
        As[ac + 6][am] = a1.z; As[ac + 7][am] = a1.w;
#pragma unroll
        for (int j = 0; j < 8; ++j) Bs[br][bn0 + j] = bv[j];
        __syncthreads();
#pragma unroll
        for (int kk = 0; kk < 16; ++kk) {
            float4 x0 = *(float4*)&As[kk][ty * 8];
            float4 x1 = *(float4*)&As[kk][ty * 8 + 4];
            float4 y0 = *(float4*)&Bs[kk][tx * 8];
            float4 y1 = *(float4*)&Bs[kk][tx * 8 + 4];
            float av[8] = {x0.x, x0.y, x0.z, x0.w, x1.x, x1.y, x1.z, x1.w};
            float bvv[8] = {y0.x, y0.y, y0.z, y0.w, y1.x, y1.y, y1.z, y1.w};
#pragma unroll
            for (int i = 0; i < 8; ++i)
#pragma unroll
                for (int j = 0; j < 8; ++j)
                    acc[i][j] = fmaf(av[i], bvv[j], acc[i][j]);
        }
        __syncthreads();
    }

#pragma unroll
    for (int i = 0; i < 8; ++i) {
        float mx = -1e30f;
#pragma unroll
        for (int j = 0; j < 8; ++j) {
            float l = acc[i][j] * SCL;
            acc[i][j] = l;
            if (bn0 + j < KP) mx = fmaxf(mx, l);
        }
        mx = fmaxf(mx, __shfl_xor(mx, 1));
        mx = fmaxf(mx, __shfl_xor(mx, 2));
        mx = fmaxf(mx, __shfl_xor(mx, 4));
        mx = fmaxf(mx, __shfl_xor(mx, 8));
        float s = 0.f;
#pragma unroll
        for (int j = 0; j < 8; ++j) {
            float e = (bn0 + j < KP) ? __expf(acc[i][j] - mx) : 0.f;
            acc[i][j] = e;
            s += e;
        }
        s += __shfl_xor(s, 1);
        s += __shfl_xor(s, 2);
        s += __shfl_xor(s, 4);
        s += __shfl_xor(s, 8);
        float inv = 1.0f / s;
#pragma unroll
        for (int j = 0; j < 8; ++j) acc[i][j] *= inv;
    }

    __syncthreads();
    if (tx < 14) {
#pragma unroll
        for (int i = 0; i < 8; ++i)
#pragma unroll
            for (int j = 0; j < 8; ++j)
                Ps[ty * 8 + i][tx * 8 + j] = acc[i][j];
    }

    const int gkr = t >> 5, gc = (t & 31) * 4;
#pragma unroll 1
    for (int ch = 0; ch < 2; ++ch) {
        const int cb = ch * 128;
        float acc2[8][8];
#pragma unroll
        for (int i = 0; i < 8; ++i)
#pragma unroll
            for (int j = 0; j < 8; ++j) acc2[i][j] = 0.f;

#pragma unroll 1
        for (int kc = 0; kc < 112; kc += 8) {
            float4 g = {0.f, 0.f, 0.f, 0.f};
            if (kc + gkr < KP)
                g = *(const float4*)&gptb[(size_t)(kc + gkr) * OIN + cb + gc];
            __syncthreads();
            *(float4*)&Gs[gkr][gc] = g;
            __syncthreads();
#pragma unroll
            for (int kk = 0; kk < 8; ++kk) {
                float pk[8];
#pragma unroll
                for (int i = 0; i < 8; ++i) pk[i] = Ps[ty * 8 + i][kc + kk];
                float4 g0 = *(float4*)&Gs[kk][tx * 8];
                float4 g1 = *(float4*)&Gs[kk][tx * 8 + 4];
                float gv[8] = {g0.x, g0.y, g0.z, g0.w, g1.x, g1.y, g1.z, g1.w};
#pragma unroll
                for (int i = 0; i < 8; ++i)
#pragma unroll
                    for (int j = 0; j < 8; ++j)
                        acc2[i][j] = fmaf(pk[i], gv[j], acc2[i][j]);
            }
        }

#pragma unroll
        for (int i = 0; i < 8; ++i) {
            int n = m0 + ty * 8 + i;
            int ci = n / 36, rr = n % 36;
            float* dst = y2rb + (size_t)ci * HWN + rr * 256 + cb + tx * 8;
            float4 v0 = {acc2[i][0], acc2[i][1], acc2[i][2], acc2[i][3]};
            float4 v1 = {acc2[i][4], acc2[i][5], acc2[i][6], acc2[i][7]};
            *(float4*)&dst[0] = v0;
            *(float4*)&dst[4] = v1;
        }
    }
}

extern "C" void kernel_launch(void* const* d_in, const int* in_sizes, int n_in,
                              void* d_out, int out_size, void* d_ws, size_t ws_size,
                              hipStream_t stream)
{
    const float* x       = (const float*)d_in[0];
    const float* phi_w   = (const float*)d_in[1];
    const float* phi_b   = (const float*)d_in[2];
    const float* theta_w = (const float*)d_in[3];
    const float* theta_b = (const float*)d_in[4];
    const float* gamma_w = (const float*)d_in[5];
    const float* gamma_b = (const float*)d_in[6];
    const float* W_w     = (const float*)d_in[7];
    const float* W_b     = (const float*)d_in[8];
    float* out = (float*)d_out;

    char* ws = (char*)d_ws;
    const size_t SZP = (size_t)NB * OIN * HWN * sizeof(float);   // 75.5 MB
    float* phi  = (float*)(ws);
    float* buf2 = (float*)(ws + SZP);                            // theta_relu, later y2_r
    char* p = ws + 2 * SZP;
    float* xp  = (float*)p;  p += (size_t)NB * CIN * KP * 4;     // [B][512][110]
    float* tp  = (float*)p;  p += (size_t)NB * OIN * KP * 4;     // [B][256][110]
    float* gpt = (float*)p;  p += (size_t)NB * KP * OIN * 4;     // [B][110][256]
    unsigned short* Wcat = (unsigned short*)p; p += 512 * 512 * 2;
    unsigned short* Wwb  = (unsigned short*)p; p += 512 * 256 * 2;

    castw_kernel<<<1536, 256, 0, stream>>>(phi_w, theta_w, W_w, Wcat, Wwb);
    gemm_kernel<512, 0><<<dim3(72, 4, NB), 256, 0, stream>>>(
        x, Wcat, phi_b, theta_b, nullptr, phi, buf2);
    pool_kernel<<<dim3(NB * CIN), 256, 0, stream>>>(x, xp);
    pool_kernel<<<dim3(NB * OIN), 256, 0, stream>>>(buf2, tp);
    gammap_kernel<<<dim3(KP, NB), 256, 0, stream>>>(xp, gamma_w, gamma_b, gpt);
    attn_kernel<<<dim3(HWN / 128, NB), 256, 0, stream>>>(phi, tp, gpt, buf2);
    gemm_kernel<256, 1><<<dim3(72, 4, NB), 256, 0, stream>>>(
        buf2, Wwb, W_b, nullptr, x, out, nullptr);
}

// Round 4
// 467.266 us; speedup vs baseline: 2.7759x; 1.5019x over previous
//
#include <hip/hip_runtime.h>

#define NB 8
#define CIN 512
#define OIN 256
#define HWN 9216
#define KP 110
#define SCL 0.10206207261596577f  // 9216^(-0.25)

typedef __attribute__((ext_vector_type(8))) short bf16x8;
typedef __attribute__((ext_vector_type(4))) float f32x4;
typedef unsigned short u16;

__device__ inline unsigned bf16_1(float a) {
    unsigned u = __builtin_bit_cast(unsigned, a);
    return (u + 0x7fffu + ((u >> 16) & 1u)) >> 16;
}
__device__ inline unsigned bf16_pack(float a, float b) {
    return bf16_1(a) | (bf16_1(b) << 16);
}
__device__ inline float b2f(u16 u) {
    return __builtin_bit_cast(float, ((unsigned)u) << 16);
}
__device__ inline int swz(int r) { return (r & 7) ^ ((r >> 3) & 7); }

// ---------------------------------------------------------------------------
// Weight cast: phi_w+theta_w -> Wcat bf16 [512][512]; W_w -> Wwb bf16 [512][256]
// ---------------------------------------------------------------------------
__global__ __launch_bounds__(256) void castw_kernel(
    const float* __restrict__ phi_w, const float* __restrict__ theta_w,
    const float* __restrict__ Ww,
    u16* __restrict__ Wcat, u16* __restrict__ Wwb)
{
    int i = blockIdx.x * 256 + threadIdx.x;
    if (i < 262144) {
        float v = (i < 131072) ? phi_w[i] : theta_w[i - 131072];
        Wcat[i] = (u16)bf16_1(v);
    } else {
        int j = i - 262144;
        Wwb[j] = (u16)bf16_1(Ww[j]);
    }
}

// ---------------------------------------------------------------------------
// MFMA GEMM: D[m=hw][n=o] = sum_k Adata[k][m] * Bw[n][k]   (per batch)
//  MODE 0: Adata fp32 (x), out bf16: relu(v+bias), split n<256->phi, else theta
//  MODE 1: Adata bf16 (y2r), out fp32: v+bias+resid(x)
//  Tile 128x128, BK=64, 4 waves, 4x4 16x16x32 frags per wave.
// ---------------------------------------------------------------------------
template<int KDIM, int MODE>
__global__ __launch_bounds__(256) void gemm_kernel(
    const void* __restrict__ Adata_,
    const u16* __restrict__ Bw,
    const float* __restrict__ b0, const float* __restrict__ b1,
    const float* __restrict__ resid,
    void* __restrict__ out0_, void* __restrict__ out1_)
{
    __shared__ short As[128 * 64];   // [m][k] bf16, swizzled 16B slots
    __shared__ short Bs[128 * 64];   // [n][k] bf16, swizzled 16B slots

    const int t = threadIdx.x;
    const int b = blockIdx.z;
    const int m0 = blockIdx.x * 128;
    const int n0 = blockIdx.y * 128;
    const int w = t >> 6, l = t & 63;
    const int wr = w >> 1, wc = w & 1;
    const int fq = l >> 4;

    f32x4 zero = {0.f, 0.f, 0.f, 0.f};
    f32x4 acc[4][4];
#pragma unroll
    for (int i = 0; i < 4; ++i)
#pragma unroll
        for (int j = 0; j < 4; ++j) acc[i][j] = zero;

    const int rb = t >> 1, sb0 = (t & 1) * 4;   // B staging map

#pragma unroll 1
    for (int kt = 0; kt < KDIM; kt += 64) {
        // ---- global loads (before barrier) ----
        float4 a0[4], a1[4];         // MODE 0
        uint4 u0[2], u1[2];          // MODE 1
        if constexpr (MODE == 0) {
            const float* Ab = (const float*)Adata_ + (size_t)b * KDIM * HWN;
            const int qa = t & 7, kp = t >> 3;
            const float* r0 = Ab + (size_t)(kt + 2 * kp) * HWN + m0 + 16 * qa;
            const float* r1 = r0 + HWN;
#pragma unroll
            for (int i = 0; i < 4; ++i) {
                a0[i] = *(const float4*)(r0 + 4 * i);
                a1[i] = *(const float4*)(r1 + 4 * i);
            }
        } else {
            const u16* Ab = (const u16*)Adata_ + (size_t)b * KDIM * HWN;
            const int qa = t & 15, kp = t >> 4;
#pragma unroll
            for (int rr = 0; rr < 2; ++rr) {
                int kk = kp + 16 * rr;
                u0[rr] = *(const uint4*)(Ab + (size_t)(kt + 2 * kk) * HWN + m0 + qa * 8);
                u1[rr] = *(const uint4*)(Ab + (size_t)(kt + 2 * kk + 1) * HWN + m0 + qa * 8);
            }
        }
        uint4 bv[4];
#pragma unroll
        for (int i = 0; i < 4; ++i)
            bv[i] = *(const uint4*)(Bw + (size_t)(n0 + rb) * KDIM + kt + (sb0 + i) * 8);

        __syncthreads();   // prior LDS reads done

        if constexpr (MODE == 0) {
            const int qa = t & 7, kp = t >> 3;
            const float* f0 = (const float*)a0;
            const float* f1 = (const float*)a1;
            int slot = kp >> 2, off = (kp & 3) << 2;
#pragma unroll
            for (int j = 0; j < 16; ++j) {
                int m = 16 * qa + j;
                *(unsigned*)((char*)As + m * 128 + ((slot ^ swz(m)) << 4) + off) =
                    bf16_pack(f0[j], f1[j]);
            }
        } else {
            const int qa = t & 15, kp = t >> 4;
#pragma unroll
            for (int rr = 0; rr < 2; ++rr) {
                int kk = kp + 16 * rr;
                int slot = kk >> 2, off = (kk & 3) << 2;
                const u16* p0 = (const u16*)&u0[rr];
                const u16* p1 = (const u16*)&u1[rr];
#pragma unroll
                for (int j = 0; j < 8; ++j) {
                    int m = qa * 8 + j;
                    *(unsigned*)((char*)As + m * 128 + ((slot ^ swz(m)) << 4) + off) =
                        (unsigned)p0[j] | ((unsigned)p1[j] << 16);
                }
            }
        }
#pragma unroll
        for (int i = 0; i < 4; ++i) {
            int s = sb0 + i;
            *(uint4*)((char*)Bs + rb * 128 + ((s ^ swz(rb)) << 4)) = bv[i];
        }
        __syncthreads();

#pragma unroll
        for (int h = 0; h < 2; ++h) {
            bf16x8 af[4], bfr[4];
#pragma unroll
            for (int mi = 0; mi < 4; ++mi) {
                int r = wr * 64 + mi * 16 + (l & 15);
                af[mi] = *(const bf16x8*)((const char*)As + r * 128 + (((h * 4 + fq) ^ swz(r)) << 4));
            }
#pragma unroll
            for (int ni = 0; ni < 4; ++ni) {
                int r = wc * 64 + ni * 16 + (l & 15);
                bfr[ni] = *(const bf16x8*)((const char*)Bs + r * 128 + (((h * 4 + fq) ^ swz(r)) << 4));
            }
#pragma unroll
            for (int mi = 0; mi < 4; ++mi)
#pragma unroll
                for (int ni = 0; ni < 4; ++ni)
                    acc[mi][ni] = __builtin_amdgcn_mfma_f32_16x16x32_bf16(
                        af[mi], bfr[ni], acc[mi][ni], 0, 0, 0);
        }
    }

    // ---- epilogue: transposed store D[m][n] -> dst[n][m] ----
#pragma unroll
    for (int ni = 0; ni < 4; ++ni) {
        int n = n0 + wc * 64 + ni * 16 + (l & 15);
        if constexpr (MODE == 0) {
            float bias = (n < 256) ? b0[n] : b1[n - 256];
            u16* dst = (u16*)((n < 256) ? out0_ : out1_) + ((size_t)b * 256 + (n & 255)) * HWN;
#pragma unroll
            for (int mi = 0; mi < 4; ++mi) {
                int m = m0 + wr * 64 + mi * 16 + (fq << 2);
                f32x4 v = acc[mi][ni];
                float e0 = fmaxf(v.x + bias, 0.f), e1 = fmaxf(v.y + bias, 0.f);
                float e2 = fmaxf(v.z + bias, 0.f), e3 = fmaxf(v.w + bias, 0.f);
                uint2 pk = {bf16_pack(e0, e1), bf16_pack(e2, e3)};
                *(uint2*)(dst + m) = pk;
            }
        } else {
            float bias = b0[n];
            float* dst = (float*)out0_ + ((size_t)b * 512 + n) * HWN;
            const float* res = resid + ((size_t)b * 512 + n) * HWN;
#pragma unroll
            for (int mi = 0; mi < 4; ++mi) {
                int m = m0 + wr * 64 + mi * 16 + (fq << 2);
                f32x4 v = acc[mi][ni];
                float4 rx = *(const float4*)(res + m);
                float4 o = {v.x + bias + rx.x, v.y + bias + rx.y,
                            v.z + bias + rx.z, v.w + bias + rx.w};
                *(float4*)(dst + m) = o;
            }
        }
    }
}

// ---------------------------------------------------------------------------
// SPP pooling, fp32 input (x) -> xp [B][512][110] fp32
// ---------------------------------------------------------------------------
__global__ __launch_bounds__(256) void pool_x_kernel(
    const float* __restrict__ in, float* __restrict__ out)
{
    __shared__ float ps[576];
    const int plane = blockIdx.x;
    const float* p = in + (size_t)plane * HWN;
    const int t = threadIdx.x;

    for (int i = t; i < 576; i += 256) {
        int bh = i / 24, bw = i % 24;
        float s = 0.f;
#pragma unroll
        for (int r = 0; r < 4; ++r) {
            float4 v = *(const float4*)&p[(bh * 4 + r) * 96 + bw * 4];
            s += v.x + v.y + v.z + v.w;
        }
        ps[i] = s;
    }
    __syncthreads();

    if (t < KP) {
        float s = 0.f;
        if (t == 0) {
            for (int i = 0; i < 576; ++i) s += ps[i];
            s *= (1.0f / 9216.0f);
        } else if (t < 10) {
            int idx = t - 1, bi = idx / 3, bj = idx % 3;
            for (int r = 0; r < 8; ++r)
                for (int c = 0; c < 8; ++c)
                    s += ps[(bi * 8 + r) * 24 + bj * 8 + c];
            s *= (1.0f / 1024.0f);
        } else if (t < 46) {
            int idx = t - 10, bi = idx / 6, bj = idx % 6;
            for (int r = 0; r < 4; ++r)
                for (int c = 0; c < 4; ++c)
                    s += ps[(bi * 4 + r) * 24 + bj * 4 + c];
            s *= (1.0f / 256.0f);
        } else {
            int idx = t - 46, bi = idx / 8, bj = idx % 8;
            for (int r = 0; r < 3; ++r)
                for (int c = 0; c < 3; ++c)
                    s += ps[(bi * 3 + r) * 24 + bj * 3 + c];
            s *= (1.0f / 144.0f);
        }
        out[(size_t)plane * KP + t] = s;
    }
}

// ---------------------------------------------------------------------------
// SPP pooling, bf16 input (theta) -> tpT [B][128][256] bf16 TRANSPOSED, n-padded
// plane = b*256 + c
// ---------------------------------------------------------------------------
__global__ __launch_bounds__(256) void pool_t_kernel(
    const u16* __restrict__ in, u16* __restrict__ outT)
{
    __shared__ float ps[576];
    const int plane = blockIdx.x;
    const int b = plane >> 8, c = plane & 255;
    const u16* p = in + (size_t)plane * HWN;
    const int t = threadIdx.x;

    for (int i = t; i < 576; i += 256) {
        int bh = i / 24, bw = i % 24;
        float s = 0.f;
#pragma unroll
        for (int r = 0; r < 4; ++r) {
            ushort4 v = *(const ushort4*)&p[(bh * 4 + r) * 96 + bw * 4];
            s += b2f(v.x) + b2f(v.y) + b2f(v.z) + b2f(v.w);
        }
        ps[i] = s;
    }
    __syncthreads();

    if (t < 128) {
        float s = 0.f;
        if (t == 0) {
            for (int i = 0; i < 576; ++i) s += ps[i];
            s *= (1.0f / 9216.0f);
        } else if (t < 10) {
            int idx = t - 1, bi = idx / 3, bj = idx % 3;
            for (int r = 0; r < 8; ++r)
                for (int cc = 0; cc < 8; ++cc)
                    s += ps[(bi * 8 + r) * 24 + bj * 8 + cc];
            s *= (1.0f / 1024.0f);
        } else if (t < 46) {
            int idx = t - 10, bi = idx / 6, bj = idx % 6;
            for (int r = 0; r < 4; ++r)
                for (int cc = 0; cc < 4; ++cc)
                    s += ps[(bi * 4 + r) * 24 + bj * 4 + cc];
            s *= (1.0f / 256.0f);
        } else if (t < KP) {
            int idx = t - 46, bi = idx / 8, bj = idx % 8;
            for (int r = 0; r < 3; ++r)
                for (int cc = 0; cc < 3; ++cc)
                    s += ps[(bi * 3 + r) * 24 + bj * 3 + cc];
            s *= (1.0f / 144.0f);
        } else {
            s = 0.f;  // pad rows 110..127
        }
        outT[((size_t)b * 128 + t) * 256 + c] = (u16)bf16_1(s);
    }
}

// ---------------------------------------------------------------------------
// gamma_p k-minor: gp[b][c][k] bf16, k padded to 128 with zeros
// grid (128, B), 256 threads = c
// ---------------------------------------------------------------------------
__global__ __launch_bounds__(256) void gammap_kernel(
    const float* __restrict__ xp,   // [B][512][110] fp32
    const float* __restrict__ gw,   // [256][512]
    const float* __restrict__ gb,   // [256]
    u16* __restrict__ gp)           // [B][256][128] bf16
{
    const int k = blockIdx.x, b = blockIdx.y;
    const int t = threadIdx.x;
    if (k >= KP) {
        gp[((size_t)b * 256 + t) * 128 + k] = 0;
        return;
    }
    __shared__ float xc[512];
    xc[t]       = xp[((size_t)b * CIN + t) * KP + k];
    xc[t + 256] = xp[((size_t)b * CIN + t + 256) * KP + k];
    __syncthreads();

    float acc = gb[t];
    const float* wrow = gw + (size_t)t * CIN;
#pragma unroll 4
    for (int c = 0; c < CIN; c += 4) {
        float4 wv = *(const float4*)&wrow[c];
        acc = fmaf(wv.x, xc[c], acc);
        acc = fmaf(wv.y, xc[c + 1], acc);
        acc = fmaf(wv.z, xc[c + 2], acc);
        acc = fmaf(wv.w, xc[c + 3], acc);
    }
    gp[((size_t)b * 256 + t) * 128 + k] = (u16)bf16_1(acc);
}

// ---------------------------------------------------------------------------
// MFMA attention. Block = 128 rows, 4 waves x 32 rows.
//  GEMM1: logits[128m][128n] = phi[m][c] x tpT[n][c]^T, K=256, A/B direct global
//  softmax in-register on D-layout (row = 16 lanes, shfl_xor 1,2,4,8)
//  P bf16 -> swizzled LDS [128][128] (wave-private rows, no barrier)
//  GEMM2: y2[128m][256c] = P[m][k] x gp[c][k]^T, K=128
//  y2 -> swizzled LDS [128][256] bf16 -> coalesced global store in y2_r layout
// ---------------------------------------------------------------------------
__global__ __launch_bounds__(256) void attn_kernel(
    const u16* __restrict__ phi,   // [B][256*9216] bf16 flat
    const u16* __restrict__ tpT,   // [B][128][256] bf16
    const u16* __restrict__ gp,    // [B][256][128] bf16
    u16* __restrict__ y2)          // [B][256][9216] bf16 (y2_r layout)
{
    __shared__ __align__(16) char smem[65536];

    const int t = threadIdx.x;
    const int w = t >> 6, l = t & 63;
    const int g = l >> 4, li = l & 15;
    const int b = blockIdx.y;
    const int m0 = blockIdx.x * 128;

    const u16* phib = phi + (size_t)b * (OIN * HWN);
    const u16* tpb  = tpT + (size_t)b * (128 * 256);
    const u16* gpb  = gp  + (size_t)b * (256 * 128);

    f32x4 zero = {0.f, 0.f, 0.f, 0.f};
    f32x4 acc[2][8];
#pragma unroll
    for (int i = 0; i < 2; ++i)
#pragma unroll
        for (int j = 0; j < 8; ++j) acc[i][j] = zero;

    const int r0 = m0 + w * 32;

    // ---------------- GEMM1 ----------------
#pragma unroll 2
    for (int ks = 0; ks < 8; ++ks) {
        const int c0 = ks * 32 + g * 8;
        bf16x8 af[2], bfr[8];
#pragma unroll
        for (int mi = 0; mi < 2; ++mi)
            af[mi] = *(const bf16x8*)(phib + (size_t)(r0 + mi * 16 + li) * 256 + c0);
#pragma unroll
        for (int ni = 0; ni < 8; ++ni)
            bfr[ni] = *(const bf16x8*)(tpb + (size_t)(ni * 16 + li) * 256 + c0);
#pragma unroll
        for (int mi = 0; mi < 2; ++mi)
#pragma unroll
            for (int ni = 0; ni < 8; ++ni)
                acc[mi][ni] = __builtin_amdgcn_mfma_f32_16x16x32_bf16(
                    af[mi], bfr[ni], acc[mi][ni], 0, 0, 0);
    }

    // ---------------- softmax + P -> LDS ----------------
    bool vm[8];
#pragma unroll
    for (int ni = 0; ni < 8; ++ni) vm[ni] = (ni * 16 + li) < KP;

#pragma unroll
    for (int mi = 0; mi < 2; ++mi) {
#pragma unroll
        for (int r = 0; r < 4; ++r) {
            float mx = -1e30f;
#pragma unroll
            for (int ni = 0; ni < 8; ++ni)
                if (vm[ni]) mx = fmaxf(mx, acc[mi][ni][r] * SCL);
            mx = fmaxf(mx, __shfl_xor(mx, 1));
            mx = fmaxf(mx, __shfl_xor(mx, 2));
            mx = fmaxf(mx, __shfl_xor(mx, 4));
            mx = fmaxf(mx, __shfl_xor(mx, 8));
            float s = 0.f;
#pragma unroll
            for (int ni = 0; ni < 8; ++ni) {
                float e = vm[ni] ? __expf(acc[mi][ni][r] * SCL - mx) : 0.f;
                acc[mi][ni][r] = e;
                s += e;
            }
            s += __shfl_xor(s, 1);
            s += __shfl_xor(s, 2);
            s += __shfl_xor(s, 4);
            s += __shfl_xor(s, 8);
            float inv = 1.0f / s;
#pragma unroll
            for (int ni = 0; ni < 8; ++ni) acc[mi][ni][r] *= inv;
        }
        // write P rows (wave-private; GEMM2 reads only own rows -> no barrier)
#pragma unroll
        for (int ni = 0; ni < 8; ++ni)
#pragma unroll
            for (int r = 0; r < 4; ++r) {
                int row = w * 32 + mi * 16 + g * 4 + r;
                int col = ni * 16 + li;
                *(short*)(smem + row * 256 + (((col >> 3) ^ (row & 7)) << 4) + ((col & 7) << 1)) =
                    (short)bf16_1(acc[mi][ni][r]);
            }
    }

    // ---------------- GEMM2 ----------------
    f32x4 acc2[2][16];
#pragma unroll
    for (int i = 0; i < 2; ++i)
#pragma unroll
        for (int j = 0; j < 16; ++j) acc2[i][j] = zero;

#pragma unroll 1
    for (int ks = 0; ks < 4; ++ks) {
        bf16x8 a2[2];
#pragma unroll
        for (int mi = 0; mi < 2; ++mi) {
            int row = w * 32 + mi * 16 + li;
            int slot = ks * 4 + g;
            a2[mi] = *(const bf16x8*)(smem + row * 256 + ((slot ^ (row & 7)) << 4));
        }
#pragma unroll
        for (int cf = 0; cf < 16; ++cf) {
            bf16x8 bv = *(const bf16x8*)(gpb + (size_t)(cf * 16 + li) * 128 + ks * 32 + g * 8);
#pragma unroll
            for (int mi = 0; mi < 2; ++mi)
                acc2[mi][cf] = __builtin_amdgcn_mfma_f32_16x16x32_bf16(
                    a2[mi], bv, acc2[mi][cf], 0, 0, 0);
        }
    }

    __syncthreads();   // all P reads done before y2l overwrites

    // ---------------- y2 -> LDS (transpose to m-major) ----------------
#pragma unroll
    for (int mi = 0; mi < 2; ++mi)
#pragma unroll
        for (int cf = 0; cf < 16; ++cf)
#pragma unroll
            for (int r = 0; r < 4; ++r) {
                int row = w * 32 + mi * 16 + g * 4 + r;
                int c = cf * 16 + li;
                *(short*)(smem + row * 512 + (((c >> 3) ^ (row & 7)) << 4) + ((c & 7) << 1)) =
                    (short)bf16_1(acc2[mi][cf][r]);
            }

    __syncthreads();

    // ---------------- coalesced store in y2_r layout ----------------
    {
        int row = t >> 1;
        int n = m0 + row, ci = n / 36, rr = n % 36;
        u16* dst = y2 + ((size_t)b * OIN + ci) * HWN + rr * 256 + (t & 1) * 128;
#pragma unroll
        for (int j = 0; j < 16; ++j) {
            int c0 = (t & 1) * 128 + j * 8;
            int slot = c0 >> 3;
            uint4 v = *(const uint4*)(smem + row * 512 + ((slot ^ (row & 7)) << 4));
            *(uint4*)(dst + j * 8) = v;
        }
    }
}

extern "C" void kernel_launch(void* const* d_in, const int* in_sizes, int n_in,
                              void* d_out, int out_size, void* d_ws, size_t ws_size,
                              hipStream_t stream)
{
    const float* x       = (const float*)d_in[0];
    const float* phi_w   = (const float*)d_in[1];
    const float* phi_b   = (const float*)d_in[2];
    const float* theta_w = (const float*)d_in[3];
    const float* theta_b = (const float*)d_in[4];
    const float* gamma_w = (const float*)d_in[5];
    const float* gamma_b = (const float*)d_in[6];
    const float* W_w     = (const float*)d_in[7];
    const float* W_b     = (const float*)d_in[8];
    float* out = (float*)d_out;

    char* p = (char*)d_ws;
    const size_t SZB = (size_t)NB * OIN * HWN * 2;               // 37.7 MB bf16
    u16* phi_bf   = (u16*)p;  p += SZB;
    u16* theta_bf = (u16*)p;  p += SZB;
    u16* y2bf     = (u16*)p;  p += SZB;
    float* xp     = (float*)p; p += (size_t)NB * CIN * KP * 4;   // [B][512][110]
    u16* tpT      = (u16*)p;  p += (size_t)NB * 128 * 256 * 2;   // [B][128][256]
    u16* gp       = (u16*)p;  p += (size_t)NB * 256 * 128 * 2;   // [B][256][128]
    u16* Wcat     = (u16*)p;  p += 512 * 512 * 2;
    u16* Wwb      = (u16*)p;  p += 512 * 256 * 2;

    castw_kernel<<<1536, 256, 0, stream>>>(phi_w, theta_w, W_w, Wcat, Wwb);
    gemm_kernel<512, 0><<<dim3(72, 4, NB), 256, 0, stream>>>(
        x, Wcat, phi_b, theta_b, nullptr, phi_bf, theta_bf);
    pool_x_kernel<<<dim3(NB * CIN), 256, 0, stream>>>(x, xp);
    pool_t_kernel<<<dim3(NB * OIN), 256, 0, stream>>>(theta_bf, tpT);
    gammap_kernel<<<dim3(128, NB), 256, 0, stream>>>(xp, gamma_w, gamma_b, gp);
    attn_kernel<<<dim3(72, NB), 256, 0, stream>>>(phi_bf, tpT, gp, y2bf);
    gemm_kernel<256, 1><<<dim3(72, 4, NB), 256, 0, stream>>>(
        y2bf, Wwb, W_b, nullptr, x, out, nullptr);
}

// Round 5
// 393.607 us; speedup vs baseline: 3.2954x; 1.1871x over previous
//
#include <hip/hip_runtime.h>

#define NB 8
#define CIN 512
#define OIN 256
#define HWN 9216
#define KP 110
#define SCL 0.10206207261596577f  // 9216^(-0.25)

typedef __attribute__((ext_vector_type(8))) short bf16x8;
typedef __attribute__((ext_vector_type(4))) float f32x4;
typedef unsigned short u16;

__device__ inline unsigned bf16_1(float a) {
    unsigned u = __builtin_bit_cast(unsigned, a);
    return (u + 0x7fffu + ((u >> 16) & 1u)) >> 16;
}
__device__ inline unsigned bf16_pack(float a, float b) {
    return bf16_1(a) | (bf16_1(b) << 16);
}
__device__ inline float b2f(u16 u) {
    return __builtin_bit_cast(float, ((unsigned)u) << 16);
}

__device__ __forceinline__ void gload16(const u16* g, u16* l) {
    __builtin_amdgcn_global_load_lds(
        (const __attribute__((address_space(1))) unsigned int*)g,
        (__attribute__((address_space(3))) unsigned int*)l, 16, 0, 0);
}

// ---------------------------------------------------------------------------
// Weight cast: phi_w+theta_w -> Wcat bf16 [512][512]; W_w -> Wwb bf16 [512][256]
// ---------------------------------------------------------------------------
__global__ __launch_bounds__(256) void castw_kernel(
    const float* __restrict__ phi_w, const float* __restrict__ theta_w,
    const float* __restrict__ Ww,
    u16* __restrict__ Wcat, u16* __restrict__ Wwb)
{
    int i = blockIdx.x * 256 + threadIdx.x;
    if (i < 262144) {
        float v = (i < 131072) ? phi_w[i] : theta_w[i - 131072];
        Wcat[i] = (u16)bf16_1(v);
    } else {
        int j = i - 262144;
        Wwb[j] = (u16)bf16_1(Ww[j]);
    }
}

// ---------------------------------------------------------------------------
// castx: x fp32 [b][512 c][9216 hw] -> xT bf16 [b][9216 hw][512 c]
// 64x64 tile per block, 4x4 micro-tile per thread, in-register transpose.
// ---------------------------------------------------------------------------
__global__ __launch_bounds__(256) void castx_kernel(
    const float* __restrict__ x, u16* __restrict__ xT)
{
    const int t = threadIdx.x;
    const int tx = t & 15, ty = t >> 4;          // tx: hw micro, ty: c micro
    const int b = blockIdx.z;
    const int c0 = blockIdx.y * 64;
    const int hw0 = blockIdx.x * 64;

    const float* xb = x + ((size_t)b * CIN + c0 + ty * 4) * HWN + hw0 + tx * 4;
    float4 v[4];
#pragma unroll
    for (int q = 0; q < 4; ++q)
        v[q] = *(const float4*)(xb + (size_t)q * HWN);

    u16* dst = xT + ((size_t)b * HWN + hw0 + tx * 4) * CIN + c0 + ty * 4;
    const float* f = (const float*)v;
#pragma unroll
    for (int p = 0; p < 4; ++p) {
        // column p of the 4x4 block -> 4 consecutive c
        uint2 o = {bf16_pack(f[0 * 4 + p], f[1 * 4 + p]),
                   bf16_pack(f[2 * 4 + p], f[3 * 4 + p])};
        *(uint2*)(dst + (size_t)p * CIN) = o;
    }
}

// ---------------------------------------------------------------------------
// MFMA GEMM (m97 structure): D[m=hw][n=o] = sum_k A[m][k] * Bw[n][k]
//  A: [B][9216][KDIM] bf16 k-minor (xT or y2T); Bw: [512][KDIM] bf16 k-minor.
//  Tile 128x128, BK=64, 4 waves, 4x4 16x16x32 frags/wave.
//  Staging: global_load_lds w=16, linear LDS dest, pre-swizzled source
//  (slot' = slot ^ (row&7)); reads use the same involution -> conflict-free.
//  MODE 0: +bias, relu -> bf16, split n<256 -> out0(phi), else out1(theta)
//  MODE 1: +bias, +resid(x fp32) -> fp32 out0
// ---------------------------------------------------------------------------
template<int KDIM, int MODE>
__global__ __launch_bounds__(256) void gemm_kernel(
    const u16* __restrict__ A,
    const u16* __restrict__ Bw,
    const float* __restrict__ b0, const float* __restrict__ b1,
    const float* __restrict__ resid,
    void* __restrict__ out0_, void* __restrict__ out1_)
{
    __shared__ u16 As[128 * 64];
    __shared__ u16 Bs[128 * 64];

    const int t = threadIdx.x;
    const int bz = blockIdx.z;
    const int m0 = blockIdx.x * 128;
    const int n0 = blockIdx.y * 128;
    const int w = t >> 6, l = t & 63;
    const int wr = w >> 1, wc = w & 1;
    const int g = l >> 4, li = l & 15;

    const u16* Ab = A + (size_t)bz * HWN * KDIM;

    const int srow = t >> 3;   // staging row (within 32-row chunk)
    const int su = t & 7;      // staging slot

    f32x4 zero = {0.f, 0.f, 0.f, 0.f};
    f32x4 acc[4][4];
#pragma unroll
    for (int i = 0; i < 4; ++i)
#pragma unroll
        for (int j = 0; j < 4; ++j) acc[i][j] = zero;

    for (int kt = 0; kt < KDIM; kt += 64) {
#pragma unroll
        for (int cc = 0; cc < 4; ++cc) {
            int row = cc * 32 + srow;
            int ss = su ^ (row & 7);
            gload16(Ab + (size_t)(m0 + row) * KDIM + kt + ss * 8,
                    &As[(row * 8 + su) * 8]);
        }
#pragma unroll
        for (int cc = 0; cc < 4; ++cc) {
            int row = cc * 32 + srow;
            int ss = su ^ (row & 7);
            gload16(Bw + (size_t)(n0 + row) * KDIM + kt + ss * 8,
                    &Bs[(row * 8 + su) * 8]);
        }
        __syncthreads();   // drains vmcnt -> staged data visible

#pragma unroll
        for (int h = 0; h < 2; ++h) {
            bf16x8 af[4], bv[4];
#pragma unroll
            for (int mi = 0; mi < 4; ++mi) {
                int r = wr * 64 + mi * 16 + li;
                af[mi] = *(const bf16x8*)&As[r * 64 + (((h * 4 + g) ^ (r & 7)) << 3)];
            }
#pragma unroll
            for (int ni = 0; ni < 4; ++ni) {
                int r = wc * 64 + ni * 16 + li;
                bv[ni] = *(const bf16x8*)&Bs[r * 64 + (((h * 4 + g) ^ (r & 7)) << 3)];
            }
#pragma unroll
            for (int mi = 0; mi < 4; ++mi)
#pragma unroll
                for (int ni = 0; ni < 4; ++ni)
                    acc[mi][ni] = __builtin_amdgcn_mfma_f32_16x16x32_bf16(
                        af[mi], bv[ni], acc[mi][ni], 0, 0, 0);
        }
        __syncthreads();   // protect LDS before next-iter staging
    }

    // ---- epilogue: transposed store D[m][n] -> dst[n][m] ----
#pragma unroll
    for (int ni = 0; ni < 4; ++ni) {
        int n = n0 + wc * 64 + ni * 16 + li;
        if constexpr (MODE == 0) {
            float bias = (n < 256) ? b0[n] : b1[n - 256];
            u16* dst = (u16*)((n < 256) ? out0_ : out1_) + ((size_t)bz * 256 + (n & 255)) * HWN;
#pragma unroll
            for (int mi = 0; mi < 4; ++mi) {
                int m = m0 + wr * 64 + mi * 16 + (g << 2);
                f32x4 v = acc[mi][ni];
                float e0 = fmaxf(v.x + bias, 0.f), e1 = fmaxf(v.y + bias, 0.f);
                float e2 = fmaxf(v.z + bias, 0.f), e3 = fmaxf(v.w + bias, 0.f);
                uint2 pk = {bf16_pack(e0, e1), bf16_pack(e2, e3)};
                *(uint2*)(dst + m) = pk;
            }
        } else {
            float bias = b0[n];
            float* dst = (float*)out0_ + ((size_t)bz * 512 + n) * HWN;
            const float* res = resid + ((size_t)bz * 512 + n) * HWN;
#pragma unroll
            for (int mi = 0; mi < 4; ++mi) {
                int m = m0 + wr * 64 + mi * 16 + (g << 2);
                f32x4 v = acc[mi][ni];
                float4 rx = *(const float4*)(res + m);
                float4 o = {v.x + bias + rx.x, v.y + bias + rx.y,
                            v.z + bias + rx.z, v.w + bias + rx.w};
                *(float4*)(dst + m) = o;
            }
        }
    }
}

// ---------------------------------------------------------------------------
// SPP pooling, fp32 input (x) -> xp [B][512][110] fp32
// ---------------------------------------------------------------------------
__global__ __launch_bounds__(256) void pool_x_kernel(
    const float* __restrict__ in, float* __restrict__ out)
{
    __shared__ float ps[576];
    const int plane = blockIdx.x;
    const float* p = in + (size_t)plane * HWN;
    const int t = threadIdx.x;

    for (int i = t; i < 576; i += 256) {
        int bh = i / 24, bw = i % 24;
        float s = 0.f;
#pragma unroll
        for (int r = 0; r < 4; ++r) {
            float4 v = *(const float4*)&p[(bh * 4 + r) * 96 + bw * 4];
            s += v.x + v.y + v.z + v.w;
        }
        ps[i] = s;
    }
    __syncthreads();

    if (t < KP) {
        float s = 0.f;
        if (t == 0) {
            for (int i = 0; i < 576; ++i) s += ps[i];
            s *= (1.0f / 9216.0f);
        } else if (t < 10) {
            int idx = t - 1, bi = idx / 3, bj = idx % 3;
            for (int r = 0; r < 8; ++r)
                for (int c = 0; c < 8; ++c)
                    s += ps[(bi * 8 + r) * 24 + bj * 8 + c];
            s *= (1.0f / 1024.0f);
        } else if (t < 46) {
            int idx = t - 10, bi = idx / 6, bj = idx % 6;
            for (int r = 0; r < 4; ++r)
                for (int c = 0; c < 4; ++c)
                    s += ps[(bi * 4 + r) * 24 + bj * 4 + c];
            s *= (1.0f / 256.0f);
        } else {
            int idx = t - 46, bi = idx / 8, bj = idx % 8;
            for (int r = 0; r < 3; ++r)
                for (int c = 0; c < 3; ++c)
                    s += ps[(bi * 3 + r) * 24 + bj * 3 + c];
            s *= (1.0f / 144.0f);
        }
        out[(size_t)plane * KP + t] = s;
    }
}

// ---------------------------------------------------------------------------
// SPP pooling, bf16 input (theta) -> tpT [B][128][256] bf16 transposed, padded
// ---------------------------------------------------------------------------
__global__ __launch_bounds__(256) void pool_t_kernel(
    const u16* __restrict__ in, u16* __restrict__ outT)
{
    __shared__ float ps[576];
    const int plane = blockIdx.x;
    const int b = plane >> 8, c = plane & 255;
    const u16* p = in + (size_t)plane * HWN;
    const int t = threadIdx.x;

    for (int i = t; i < 576; i += 256) {
        int bh = i / 24, bw = i % 24;
        float s = 0.f;
#pragma unroll
        for (int r = 0; r < 4; ++r) {
            ushort4 v = *(const ushort4*)&p[(bh * 4 + r) * 96 + bw * 4];
            s += b2f(v.x) + b2f(v.y) + b2f(v.z) + b2f(v.w);
        }
        ps[i] = s;
    }
    __syncthreads();

    if (t < 128) {
        float s = 0.f;
        if (t == 0) {
            for (int i = 0; i < 576; ++i) s += ps[i];
            s *= (1.0f / 9216.0f);
        } else if (t < 10) {
            int idx = t - 1, bi = idx / 3, bj = idx % 3;
            for (int r = 0; r < 8; ++r)
                for (int cc = 0; cc < 8; ++cc)
                    s += ps[(bi * 8 + r) * 24 + bj * 8 + cc];
            s *= (1.0f / 1024.0f);
        } else if (t < 46) {
            int idx = t - 10, bi = idx / 6, bj = idx % 6;
            for (int r = 0; r < 4; ++r)
                for (int cc = 0; cc < 4; ++cc)
                    s += ps[(bi * 4 + r) * 24 + bj * 4 + cc];
            s *= (1.0f / 256.0f);
        } else if (t < KP) {
            int idx = t - 46, bi = idx / 8, bj = idx % 8;
            for (int r = 0; r < 3; ++r)
                for (int cc = 0; cc < 3; ++cc)
                    s += ps[(bi * 3 + r) * 24 + bj * 3 + cc];
            s *= (1.0f / 144.0f);
        } else {
            s = 0.f;
        }
        outT[((size_t)b * 128 + t) * 256 + c] = (u16)bf16_1(s);
    }
}

// ---------------------------------------------------------------------------
// gamma_p k-minor: gp[b][c][k] bf16, k padded to 128 with zeros
// ---------------------------------------------------------------------------
__global__ __launch_bounds__(256) void gammap_kernel(
    const float* __restrict__ xp,
    const float* __restrict__ gw,
    const float* __restrict__ gb,
    u16* __restrict__ gp)
{
    const int k = blockIdx.x, b = blockIdx.y;
    const int t = threadIdx.x;
    if (k >= KP) {
        gp[((size_t)b * 256 + t) * 128 + k] = 0;
        return;
    }
    __shared__ float xc[512];
    xc[t]       = xp[((size_t)b * CIN + t) * KP + k];
    xc[t + 256] = xp[((size_t)b * CIN + t + 256) * KP + k];
    __syncthreads();

    float acc = gb[t];
    const float* wrow = gw + (size_t)t * CIN;
#pragma unroll 4
    for (int c = 0; c < CIN; c += 4) {
        float4 wv = *(const float4*)&wrow[c];
        acc = fmaf(wv.x, xc[c], acc);
        acc = fmaf(wv.y, xc[c + 1], acc);
        acc = fmaf(wv.z, xc[c + 2], acc);
        acc = fmaf(wv.w, xc[c + 3], acc);
    }
    gp[((size_t)b * 256 + t) * 128 + k] = (u16)bf16_1(acc);
}

// ---------------------------------------------------------------------------
// MFMA attention. Block = (rr, ci-half): rows n = rr + 36*ci, ci in [ci0,ci0+128).
// With this mapping the raw-reshape coords are ci_resh = ci, hw' = rr*256 + c,
// so the block's y2 output is a dense [256 hw'][128 ci] tile -> write y2T
// (k-minor for convw) via LDS transpose at zero extra cost.
// ---------------------------------------------------------------------------
__global__ __launch_bounds__(256) void attn_kernel(
    const u16* __restrict__ phi,   // [B][256][9216] bf16 (raw-reshape flat view)
    const u16* __restrict__ tpT,   // [B][128][256] bf16
    const u16* __restrict__ gp,    // [B][256][128] bf16
    u16* __restrict__ y2T)         // [B][9216 hw'][256 ci] bf16
{
    __shared__ __align__(16) char smem[65536];

    const int t = threadIdx.x;
    const int w = t >> 6, l = t & 63;
    const int g = l >> 4, li = l & 15;
    const int b = blockIdx.y;
    const int rr = blockIdx.x >> 1;          // 0..35
    const int ci0 = (blockIdx.x & 1) << 7;   // 0 or 128

    const u16* phib = phi + (size_t)b * (OIN * HWN);
    const u16* tpb  = tpT + (size_t)b * (128 * 256);
    const u16* gpb  = gp  + (size_t)b * (256 * 128);

    f32x4 zero = {0.f, 0.f, 0.f, 0.f};
    f32x4 acc[2][8];
#pragma unroll
    for (int i = 0; i < 2; ++i)
#pragma unroll
        for (int j = 0; j < 8; ++j) acc[i][j] = zero;

    // ---------------- GEMM1: logits[ci_local][token] ----------------
#pragma unroll 2
    for (int ks = 0; ks < 8; ++ks) {
        const int c0 = ks * 32 + g * 8;
        bf16x8 af[2], bfr[8];
#pragma unroll
        for (int mi = 0; mi < 2; ++mi) {
            int n = rr + 36 * (ci0 + w * 32 + mi * 16 + li);
            af[mi] = *(const bf16x8*)(phib + (size_t)n * 256 + c0);
        }
#pragma unroll
        for (int ni = 0; ni < 8; ++ni)
            bfr[ni] = *(const bf16x8*)(tpb + (size_t)(ni * 16 + li) * 256 + c0);
#pragma unroll
        for (int mi = 0; mi < 2; ++mi)
#pragma unroll
            for (int ni = 0; ni < 8; ++ni)
                acc[mi][ni] = __builtin_amdgcn_mfma_f32_16x16x32_bf16(
                    af[mi], bfr[ni], acc[mi][ni], 0, 0, 0);
    }

    // ---------------- softmax over tokens (110 valid) ----------------
    bool vm[8];
#pragma unroll
    for (int ni = 0; ni < 8; ++ni) vm[ni] = (ni * 16 + li) < KP;

#pragma unroll
    for (int mi = 0; mi < 2; ++mi) {
#pragma unroll
        for (int r = 0; r < 4; ++r) {
            float mx = -1e30f;
#pragma unroll
            for (int ni = 0; ni < 8; ++ni)
                if (vm[ni]) mx = fmaxf(mx, acc[mi][ni][r] * SCL);
            mx = fmaxf(mx, __shfl_xor(mx, 1));
            mx = fmaxf(mx, __shfl_xor(mx, 2));
            mx = fmaxf(mx, __shfl_xor(mx, 4));
            mx = fmaxf(mx, __shfl_xor(mx, 8));
            float s = 0.f;
#pragma unroll
            for (int ni = 0; ni < 8; ++ni) {
                float e = vm[ni] ? __expf(acc[mi][ni][r] * SCL - mx) : 0.f;
                acc[mi][ni][r] = e;
                s += e;
            }
            s += __shfl_xor(s, 1);
            s += __shfl_xor(s, 2);
            s += __shfl_xor(s, 4);
            s += __shfl_xor(s, 8);
            float inv = 1.0f / s;
#pragma unroll
            for (int ni = 0; ni < 8; ++ni) acc[mi][ni][r] *= inv;
        }
        // P rows -> LDS (wave-private; GEMM2 reads only own rows)
#pragma unroll
        for (int ni = 0; ni < 8; ++ni)
#pragma unroll
            for (int r = 0; r < 4; ++r) {
                int row = w * 32 + mi * 16 + g * 4 + r;
                int col = ni * 16 + li;
                *(short*)(smem + row * 256 + (((col >> 3) ^ (row & 7)) << 4) + ((col & 7) << 1)) =
                    (short)bf16_1(acc[mi][ni][r]);
            }
    }

    // ---------------- GEMM2: y2[ci_local][c] = P x gp^T ----------------
    f32x4 acc2[2][16];
#pragma unroll
    for (int i = 0; i < 2; ++i)
#pragma unroll
        for (int j = 0; j < 16; ++j) acc2[i][j] = zero;

#pragma unroll 1
    for (int ks = 0; ks < 4; ++ks) {
        bf16x8 a2[2];
#pragma unroll
        for (int mi = 0; mi < 2; ++mi) {
            int row = w * 32 + mi * 16 + li;
            int slot = ks * 4 + g;
            a2[mi] = *(const bf16x8*)(smem + row * 256 + ((slot ^ (row & 7)) << 4));
        }
#pragma unroll
        for (int cf = 0; cf < 16; ++cf) {
            bf16x8 bv = *(const bf16x8*)(gpb + (size_t)(cf * 16 + li) * 128 + ks * 32 + g * 8);
#pragma unroll
            for (int mi = 0; mi < 2; ++mi)
                acc2[mi][cf] = __builtin_amdgcn_mfma_f32_16x16x32_bf16(
                    a2[mi], bv, acc2[mi][cf], 0, 0, 0);
        }
    }

    __syncthreads();   // all P reads done before y2 tile overwrites

    // ---------------- y2 -> LDS as [c][ci^swz] ----------------
#pragma unroll
    for (int mi = 0; mi < 2; ++mi)
#pragma unroll
        for (int cf = 0; cf < 16; ++cf) {
            int c = cf * 16 + li;
            int cib = w * 32 + mi * 16 + g * 4;
            int e0 = c * 128 + (cib ^ (li << 3));
            unsigned d0 = bf16_pack(acc2[mi][cf][0], acc2[mi][cf][1]);
            unsigned d1 = bf16_pack(acc2[mi][cf][2], acc2[mi][cf][3]);
            *(unsigned*)(smem + (size_t)e0 * 2) = d0;
            *(unsigned*)(smem + (size_t)e0 * 2 + 4) = d1;
        }

    __syncthreads();

    // ---------------- coalesced y2T store ----------------
    {
        u16* yb = y2T + ((size_t)b * HWN + rr * 256) * 256 + ci0;
#pragma unroll
        for (int j = 0; j < 16; ++j) {
            int c = (t >> 4) + (j << 4);
            int e = c * 128 + (((t & 15) ^ (t >> 4)) << 3);
            uint4 v = *(const uint4*)(smem + (size_t)e * 2);
            *(uint4*)(yb + (size_t)c * 256 + (t & 15) * 8) = v;
        }
    }
}

extern "C" void kernel_launch(void* const* d_in, const int* in_sizes, int n_in,
                              void* d_out, int out_size, void* d_ws, size_t ws_size,
                              hipStream_t stream)
{
    const float* x       = (const float*)d_in[0];
    const float* phi_w   = (const float*)d_in[1];
    const float* phi_b   = (const float*)d_in[2];
    const float* theta_w = (const float*)d_in[3];
    const float* theta_b = (const float*)d_in[4];
    const float* gamma_w = (const float*)d_in[5];
    const float* gamma_b = (const float*)d_in[6];
    const float* W_w     = (const float*)d_in[7];
    const float* W_b     = (const float*)d_in[8];
    float* out = (float*)d_out;

    char* p = (char*)d_ws;
    u16* xT     = (u16*)p;  p += (size_t)NB * HWN * CIN * 2;   // 75.5 MB
    u16* phi_bf = (u16*)p;  p += (size_t)NB * OIN * HWN * 2;   // 37.7 MB
    u16* th_y2  = (u16*)p;  p += (size_t)NB * OIN * HWN * 2;   // 37.7 MB (theta, then y2T)
    float* xp   = (float*)p; p += (size_t)NB * CIN * KP * 4;
    u16* tpT    = (u16*)p;  p += (size_t)NB * 128 * 256 * 2;
    u16* gp     = (u16*)p;  p += (size_t)NB * 256 * 128 * 2;
    u16* Wcat   = (u16*)p;  p += 512 * 512 * 2;
    u16* Wwb    = (u16*)p;  p += 512 * 256 * 2;

    castw_kernel<<<1536, 256, 0, stream>>>(phi_w, theta_w, W_w, Wcat, Wwb);
    castx_kernel<<<dim3(144, 8, NB), 256, 0, stream>>>(x, xT);
    gemm_kernel<512, 0><<<dim3(72, 4, NB), 256, 0, stream>>>(
        xT, Wcat, phi_b, theta_b, nullptr, phi_bf, th_y2);
    pool_x_kernel<<<dim3(NB * CIN), 256, 0, stream>>>(x, xp);
    pool_t_kernel<<<dim3(NB * OIN), 256, 0, stream>>>(th_y2, tpT);
    gammap_kernel<<<dim3(128, NB), 256, 0, stream>>>(xp, gamma_w, gamma_b, gp);
    attn_kernel<<<dim3(72, NB), 256, 0, stream>>>(phi_bf, tpT, gp, th_y2);
    gemm_kernel<256, 1><<<dim3(72, 4, NB), 256, 0, stream>>>(
        th_y2, Wwb, W_b, nullptr, x, out, nullptr);
}

// Round 6
// 365.822 us; speedup vs baseline: 3.5457x; 1.0760x over previous
//
#include <hip/hip_runtime.h>

#define NB 8
#define CIN 512
#define OIN 256
#define HWN 9216
#define KP 110
#define SCL 0.10206207261596577f  // 9216^(-0.25)

typedef __attribute__((ext_vector_type(8))) short bf16x8;
typedef __attribute__((ext_vector_type(4))) float f32x4;
typedef unsigned short u16;

__device__ inline unsigned bf16_1(float a) {
    unsigned u = __builtin_bit_cast(unsigned, a);
    return (u + 0x7fffu + ((u >> 16) & 1u)) >> 16;
}
__device__ inline unsigned bf16_pack(float a, float b) {
    return bf16_1(a) | (bf16_1(b) << 16);
}
__device__ inline float b2f(u16 u) {
    return __builtin_bit_cast(float, ((unsigned)u) << 16);
}

__device__ __forceinline__ void gload16(const u16* g, u16* l) {
    __builtin_amdgcn_global_load_lds(
        (const __attribute__((address_space(1))) unsigned int*)g,
        (__attribute__((address_space(3))) unsigned int*)l, 16, 0, 0);
}

// ---------------------------------------------------------------------------
// Weight cast: phi_w+theta_w -> Wcat bf16 [512][512]; W_w -> Wwb bf16 [512][256]
// ---------------------------------------------------------------------------
__global__ __launch_bounds__(256) void castw_kernel(
    const float* __restrict__ phi_w, const float* __restrict__ theta_w,
    const float* __restrict__ Ww,
    u16* __restrict__ Wcat, u16* __restrict__ Wwb)
{
    int i = blockIdx.x * 256 + threadIdx.x;
    if (i < 262144) {
        float v = (i < 131072) ? phi_w[i] : theta_w[i - 131072];
        Wcat[i] = (u16)bf16_1(v);
    } else {
        int j = i - 262144;
        Wwb[j] = (u16)bf16_1(Ww[j]);
    }
}

// ---------------------------------------------------------------------------
// castx: x fp32 [b][512 c][9216 hw] -> xT bf16 [b][9216 hw][512 c]
// ---------------------------------------------------------------------------
__global__ __launch_bounds__(256) void castx_kernel(
    const float* __restrict__ x, u16* __restrict__ xT)
{
    const int t = threadIdx.x;
    const int tx = t & 15, ty = t >> 4;
    const int b = blockIdx.z;
    const int c0 = blockIdx.y * 64;
    const int hw0 = blockIdx.x * 64;

    const float* xb = x + ((size_t)b * CIN + c0 + ty * 4) * HWN + hw0 + tx * 4;
    float4 v[4];
#pragma unroll
    for (int q = 0; q < 4; ++q)
        v[q] = *(const float4*)(xb + (size_t)q * HWN);

    u16* dst = xT + ((size_t)b * HWN + hw0 + tx * 4) * CIN + c0 + ty * 4;
    const float* f = (const float*)v;
#pragma unroll
    for (int p = 0; p < 4; ++p) {
        uint2 o = {bf16_pack(f[0 * 4 + p], f[1 * 4 + p]),
                   bf16_pack(f[2 * 4 + p], f[3 * 4 + p])};
        *(uint2*)(dst + (size_t)p * CIN) = o;
    }
}

// ---------------------------------------------------------------------------
// MFMA GEMM (m97 structure): D[m=hw][n=o] = sum_k A[m][k] * Bw[n][k]
// ---------------------------------------------------------------------------
template<int KDIM, int MODE>
__global__ __launch_bounds__(256) void gemm_kernel(
    const u16* __restrict__ A,
    const u16* __restrict__ Bw,
    const float* __restrict__ b0, const float* __restrict__ b1,
    const float* __restrict__ resid,
    void* __restrict__ out0_, void* __restrict__ out1_)
{
    __shared__ u16 As[128 * 64];
    __shared__ u16 Bs[128 * 64];

    const int t = threadIdx.x;
    const int bz = blockIdx.z;
    const int m0 = blockIdx.x * 128;
    const int n0 = blockIdx.y * 128;
    const int w = t >> 6, l = t & 63;
    const int wr = w >> 1, wc = w & 1;
    const int g = l >> 4, li = l & 15;

    const u16* Ab = A + (size_t)bz * HWN * KDIM;

    const int srow = t >> 3;
    const int su = t & 7;

    f32x4 zero = {0.f, 0.f, 0.f, 0.f};
    f32x4 acc[4][4];
#pragma unroll
    for (int i = 0; i < 4; ++i)
#pragma unroll
        for (int j = 0; j < 4; ++j) acc[i][j] = zero;

    for (int kt = 0; kt < KDIM; kt += 64) {
#pragma unroll
        for (int cc = 0; cc < 4; ++cc) {
            int row = cc * 32 + srow;
            int ss = su ^ (row & 7);
            gload16(Ab + (size_t)(m0 + row) * KDIM + kt + ss * 8,
                    &As[(row * 8 + su) * 8]);
        }
#pragma unroll
        for (int cc = 0; cc < 4; ++cc) {
            int row = cc * 32 + srow;
            int ss = su ^ (row & 7);
            gload16(Bw + (size_t)(n0 + row) * KDIM + kt + ss * 8,
                    &Bs[(row * 8 + su) * 8]);
        }
        __syncthreads();

#pragma unroll
        for (int h = 0; h < 2; ++h) {
            bf16x8 af[4], bv[4];
#pragma unroll
            for (int mi = 0; mi < 4; ++mi) {
                int r = wr * 64 + mi * 16 + li;
                af[mi] = *(const bf16x8*)&As[r * 64 + (((h * 4 + g) ^ (r & 7)) << 3)];
            }
#pragma unroll
            for (int ni = 0; ni < 4; ++ni) {
                int r = wc * 64 + ni * 16 + li;
                bv[ni] = *(const bf16x8*)&Bs[r * 64 + (((h * 4 + g) ^ (r & 7)) << 3)];
            }
#pragma unroll
            for (int mi = 0; mi < 4; ++mi)
#pragma unroll
                for (int ni = 0; ni < 4; ++ni)
                    acc[mi][ni] = __builtin_amdgcn_mfma_f32_16x16x32_bf16(
                        af[mi], bv[ni], acc[mi][ni], 0, 0, 0);
        }
        __syncthreads();
    }

#pragma unroll
    for (int ni = 0; ni < 4; ++ni) {
        int n = n0 + wc * 64 + ni * 16 + li;
        if constexpr (MODE == 0) {
            float bias = (n < 256) ? b0[n] : b1[n - 256];
            u16* dst = (u16*)((n < 256) ? out0_ : out1_) + ((size_t)bz * 256 + (n & 255)) * HWN;
#pragma unroll
            for (int mi = 0; mi < 4; ++mi) {
                int m = m0 + wr * 64 + mi * 16 + (g << 2);
                f32x4 v = acc[mi][ni];
                float e0 = fmaxf(v.x + bias, 0.f), e1 = fmaxf(v.y + bias, 0.f);
                float e2 = fmaxf(v.z + bias, 0.f), e3 = fmaxf(v.w + bias, 0.f);
                uint2 pk = {bf16_pack(e0, e1), bf16_pack(e2, e3)};
                *(uint2*)(dst + m) = pk;
            }
        } else {
            float bias = b0[n];
            float* dst = (float*)out0_ + ((size_t)bz * 512 + n) * HWN;
            const float* res = resid + ((size_t)bz * 512 + n) * HWN;
#pragma unroll
            for (int mi = 0; mi < 4; ++mi) {
                int m = m0 + wr * 64 + mi * 16 + (g << 2);
                f32x4 v = acc[mi][ni];
                float4 rx = *(const float4*)(res + m);
                float4 o = {v.x + bias + rx.x, v.y + bias + rx.y,
                            v.z + bias + rx.z, v.w + bias + rx.w};
                *(float4*)(dst + m) = o;
            }
        }
    }
}

// ---------------------------------------------------------------------------
// SPP pooling, fp32 input (x) -> xp [B][512][110] fp32
// ---------------------------------------------------------------------------
__global__ __launch_bounds__(256) void pool_x_kernel(
    const float* __restrict__ in, float* __restrict__ out)
{
    __shared__ float ps[576];
    const int plane = blockIdx.x;
    const float* p = in + (size_t)plane * HWN;
    const int t = threadIdx.x;

    for (int i = t; i < 576; i += 256) {
        int bh = i / 24, bw = i % 24;
        float s = 0.f;
#pragma unroll
        for (int r = 0; r < 4; ++r) {
            float4 v = *(const float4*)&p[(bh * 4 + r) * 96 + bw * 4];
            s += v.x + v.y + v.z + v.w;
        }
        ps[i] = s;
    }
    __syncthreads();

    if (t < KP) {
        float s = 0.f;
        if (t == 0) {
            for (int i = 0; i < 576; ++i) s += ps[i];
            s *= (1.0f / 9216.0f);
        } else if (t < 10) {
            int idx = t - 1, bi = idx / 3, bj = idx % 3;
            for (int r = 0; r < 8; ++r)
                for (int c = 0; c < 8; ++c)
                    s += ps[(bi * 8 + r) * 24 + bj * 8 + c];
            s *= (1.0f / 1024.0f);
        } else if (t < 46) {
            int idx = t - 10, bi = idx / 6, bj = idx % 6;
            for (int r = 0; r < 4; ++r)
                for (int c = 0; c < 4; ++c)
                    s += ps[(bi * 4 + r) * 24 + bj * 4 + c];
            s *= (1.0f / 256.0f);
        } else {
            int idx = t - 46, bi = idx / 8, bj = idx % 8;
            for (int r = 0; r < 3; ++r)
                for (int c = 0; c < 3; ++c)
                    s += ps[(bi * 3 + r) * 24 + bj * 3 + c];
            s *= (1.0f / 144.0f);
        }
        out[(size_t)plane * KP + t] = s;
    }
}

// ---------------------------------------------------------------------------
// SPP pooling, bf16 input (theta) -> tpT [B][128][256] bf16 transposed, padded
// ---------------------------------------------------------------------------
__global__ __launch_bounds__(256) void pool_t_kernel(
    const u16* __restrict__ in, u16* __restrict__ outT)
{
    __shared__ float ps[576];
    const int plane = blockIdx.x;
    const int b = plane >> 8, c = plane & 255;
    const u16* p = in + (size_t)plane * HWN;
    const int t = threadIdx.x;

    for (int i = t; i < 576; i += 256) {
        int bh = i / 24, bw = i % 24;
        float s = 0.f;
#pragma unroll
        for (int r = 0; r < 4; ++r) {
            ushort4 v = *(const ushort4*)&p[(bh * 4 + r) * 96 + bw * 4];
            s += b2f(v.x) + b2f(v.y) + b2f(v.z) + b2f(v.w);
        }
        ps[i] = s;
    }
    __syncthreads();

    if (t < 128) {
        float s = 0.f;
        if (t == 0) {
            for (int i = 0; i < 576; ++i) s += ps[i];
            s *= (1.0f / 9216.0f);
        } else if (t < 10) {
            int idx = t - 1, bi = idx / 3, bj = idx % 3;
            for (int r = 0; r < 8; ++r)
                for (int cc = 0; cc < 8; ++cc)
                    s += ps[(bi * 8 + r) * 24 + bj * 8 + cc];
            s *= (1.0f / 1024.0f);
        } else if (t < 46) {
            int idx = t - 10, bi = idx / 6, bj = idx % 6;
            for (int r = 0; r < 4; ++r)
                for (int cc = 0; cc < 4; ++cc)
                    s += ps[(bi * 4 + r) * 24 + bj * 4 + cc];
            s *= (1.0f / 256.0f);
        } else if (t < KP) {
            int idx = t - 46, bi = idx / 8, bj = idx % 8;
            for (int r = 0; r < 3; ++r)
                for (int cc = 0; cc < 3; ++cc)
                    s += ps[(bi * 3 + r) * 24 + bj * 3 + cc];
            s *= (1.0f / 144.0f);
        } else {
            s = 0.f;
        }
        outT[((size_t)b * 128 + t) * 256 + c] = (u16)bf16_1(s);
    }
}

// ---------------------------------------------------------------------------
// gamma_p k-minor: gp[b][c][k] bf16, k padded to 128 with zeros
// ---------------------------------------------------------------------------
__global__ __launch_bounds__(256) void gammap_kernel(
    const float* __restrict__ xp,
    const float* __restrict__ gw,
    const float* __restrict__ gb,
    u16* __restrict__ gp)
{
    const int k = blockIdx.x, b = blockIdx.y;
    const int t = threadIdx.x;
    if (k >= KP) {
        gp[((size_t)b * 256 + t) * 128 + k] = 0;
        return;
    }
    __shared__ float xc[512];
    xc[t]       = xp[((size_t)b * CIN + t) * KP + k];
    xc[t + 256] = xp[((size_t)b * CIN + t + 256) * KP + k];
    __syncthreads();

    float acc = gb[t];
    const float* wrow = gw + (size_t)t * CIN;
#pragma unroll 4
    for (int c = 0; c < CIN; c += 4) {
        float4 wv = *(const float4*)&wrow[c];
        acc = fmaf(wv.x, xc[c], acc);
        acc = fmaf(wv.y, xc[c + 1], acc);
        acc = fmaf(wv.z, xc[c + 2], acc);
        acc = fmaf(wv.w, xc[c + 3], acc);
    }
    gp[((size_t)b * 256 + t) * 128 + k] = (u16)bf16_1(acc);
}

// ---------------------------------------------------------------------------
// MFMA attention with m97-style LDS staging.
// Block = (rr, ci-half): rows n = rr + 36*ci, ci in [ci0, ci0+128).
// phi_r[n][c] = phi[ci][rr*256+c]  -> A-tile = phi[ci0..+128][rr*256..+256].
// LDS map (64 KB):
//   region A (0..32KB):  As [128][64] + Bs [128][64] staging (GEMM1),
//                        then gp chunks [256][64] (GEMM2)
//   region B (32..64KB): P [128 ci][128 tok] bf16, 16B-slot XOR swizzle
//   whole 64KB:          y2 transpose tile [256 c][128 ci] (after P reads done)
// ---------------------------------------------------------------------------
__global__ __launch_bounds__(256) void attn_kernel(
    const u16* __restrict__ phi,   // [B][256][9216] bf16
    const u16* __restrict__ tpT,   // [B][128][256] bf16
    const u16* __restrict__ gp,    // [B][256][128] bf16
    u16* __restrict__ y2T)         // [B][9216 hw'][256 ci] bf16
{
    __shared__ __align__(16) u16 smem[32768];   // 64 KB
    u16* As = smem;                  // 8192 u16
    u16* Bs = smem + 8192;           // 8192 u16
    char* Pb = (char*)(smem + 16384);  // 32 KB P region

    const int t = threadIdx.x;
    const int w = t >> 6, l = t & 63;
    const int g = l >> 4, li = l & 15;
    const int b = blockIdx.y;
    const int rr = blockIdx.x >> 1;          // 0..35
    const int ci0 = (blockIdx.x & 1) << 7;   // 0 or 128

    const u16* phib = phi + (size_t)b * (OIN * HWN);
    const u16* tpb  = tpT + (size_t)b * (128 * 256);
    const u16* gpb  = gp  + (size_t)b * (256 * 128);

    const int srow = t >> 3;   // 0..31
    const int su = t & 7;

    f32x4 zero = {0.f, 0.f, 0.f, 0.f};
    f32x4 acc[2][8];
#pragma unroll
    for (int i = 0; i < 2; ++i)
#pragma unroll
        for (int j = 0; j < 8; ++j) acc[i][j] = zero;

    // ---------------- GEMM1: logits[128 ci][128 tok], K=256, BK=64 ----------
    for (int kt = 0; kt < 256; kt += 64) {
#pragma unroll
        for (int cc = 0; cc < 4; ++cc) {
            int row = cc * 32 + srow;                  // ci-local
            int ss = su ^ (row & 7);
            gload16(phib + (size_t)(ci0 + row) * HWN + rr * 256 + kt + ss * 8,
                    &As[(row * 8 + su) * 8]);
        }
#pragma unroll
        for (int cc = 0; cc < 4; ++cc) {
            int row = cc * 32 + srow;                  // tok
            int ss = su ^ (row & 7);
            gload16(tpb + (size_t)row * 256 + kt + ss * 8,
                    &Bs[(row * 8 + su) * 8]);
        }
        __syncthreads();

#pragma unroll
        for (int h = 0; h < 2; ++h) {
            bf16x8 af[2], bfr[8];
#pragma unroll
            for (int mi = 0; mi < 2; ++mi) {
                int r = w * 32 + mi * 16 + li;
                af[mi] = *(const bf16x8*)&As[r * 64 + (((h * 4 + g) ^ (r & 7)) << 3)];
            }
#pragma unroll
            for (int ni = 0; ni < 8; ++ni) {
                int r = ni * 16 + li;
                bfr[ni] = *(const bf16x8*)&Bs[r * 64 + (((h * 4 + g) ^ (r & 7)) << 3)];
            }
#pragma unroll
            for (int mi = 0; mi < 2; ++mi)
#pragma unroll
                for (int ni = 0; ni < 8; ++ni)
                    acc[mi][ni] = __builtin_amdgcn_mfma_f32_16x16x32_bf16(
                        af[mi], bfr[ni], acc[mi][ni], 0, 0, 0);
        }
        __syncthreads();
    }

    // ---------------- softmax over tokens (110 valid) ----------------
    bool vm[8];
#pragma unroll
    for (int ni = 0; ni < 8; ++ni) vm[ni] = (ni * 16 + li) < KP;

#pragma unroll
    for (int mi = 0; mi < 2; ++mi) {
#pragma unroll
        for (int r = 0; r < 4; ++r) {
            float mx = -1e30f;
#pragma unroll
            for (int ni = 0; ni < 8; ++ni)
                if (vm[ni]) mx = fmaxf(mx, acc[mi][ni][r] * SCL);
            mx = fmaxf(mx, __shfl_xor(mx, 1));
            mx = fmaxf(mx, __shfl_xor(mx, 2));
            mx = fmaxf(mx, __shfl_xor(mx, 4));
            mx = fmaxf(mx, __shfl_xor(mx, 8));
            float s = 0.f;
#pragma unroll
            for (int ni = 0; ni < 8; ++ni) {
                float e = vm[ni] ? __expf(acc[mi][ni][r] * SCL - mx) : 0.f;
                acc[mi][ni][r] = e;
                s += e;
            }
            s += __shfl_xor(s, 1);
            s += __shfl_xor(s, 2);
            s += __shfl_xor(s, 4);
            s += __shfl_xor(s, 8);
            float inv = 1.0f / s;
#pragma unroll
            for (int ni = 0; ni < 8; ++ni) acc[mi][ni][r] *= inv;
        }
        // P rows -> region B (wave-private rows; region untouched by GEMM1)
#pragma unroll
        for (int ni = 0; ni < 8; ++ni)
#pragma unroll
            for (int r = 0; r < 4; ++r) {
                int row = w * 32 + mi * 16 + g * 4 + r;
                int col = ni * 16 + li;
                *(short*)(Pb + row * 256 + (((col >> 3) ^ (row & 7)) << 4) + ((col & 7) << 1)) =
                    (short)bf16_1(acc[mi][ni][r]);
            }
    }

    // ---------------- GEMM2: y2[128 ci][256 c], K=128 tok, 2 chunks ---------
    f32x4 acc2[2][16];
#pragma unroll
    for (int i = 0; i < 2; ++i)
#pragma unroll
        for (int j = 0; j < 16; ++j) acc2[i][j] = zero;

#pragma unroll 1
    for (int ks2 = 0; ks2 < 2; ++ks2) {
        // stage gp chunk [256 c][64 tok] into region A (32 KB)
#pragma unroll
        for (int cc = 0; cc < 8; ++cc) {
            int row = cc * 32 + srow;                  // c
            int ss = su ^ (row & 7);
            gload16(gpb + (size_t)row * 128 + ks2 * 64 + ss * 8,
                    &smem[(row * 8 + su) * 8]);
        }
        __syncthreads();

#pragma unroll
        for (int h = 0; h < 2; ++h) {
            bf16x8 a2[2];
#pragma unroll
            for (int mi = 0; mi < 2; ++mi) {
                int prow = w * 32 + mi * 16 + li;
                int s = ks2 * 8 + h * 4 + g;
                a2[mi] = *(const bf16x8*)(Pb + prow * 256 + ((s ^ (prow & 7)) << 4));
            }
#pragma unroll
            for (int cf = 0; cf < 16; ++cf) {
                int crow = cf * 16 + li;
                bf16x8 bv = *(const bf16x8*)&smem[crow * 64 + (((h * 4 + g) ^ (crow & 7)) << 3)];
#pragma unroll
                for (int mi = 0; mi < 2; ++mi)
                    acc2[mi][cf] = __builtin_amdgcn_mfma_f32_16x16x32_bf16(
                        a2[mi], bv, acc2[mi][cf], 0, 0, 0);
            }
        }
        __syncthreads();
    }

    // ---------------- y2 -> LDS as [c][ci^swz] over whole 64 KB -------------
#pragma unroll
    for (int mi = 0; mi < 2; ++mi)
#pragma unroll
        for (int cf = 0; cf < 16; ++cf) {
            int c = cf * 16 + li;
            int cib = w * 32 + mi * 16 + g * 4;
            int e0 = c * 128 + (cib ^ (li << 3));
            unsigned d0 = bf16_pack(acc2[mi][cf][0], acc2[mi][cf][1]);
            unsigned d1 = bf16_pack(acc2[mi][cf][2], acc2[mi][cf][3]);
            *(unsigned*)((char*)smem + (size_t)e0 * 2) = d0;
            *(unsigned*)((char*)smem + (size_t)e0 * 2 + 4) = d1;
        }

    __syncthreads();

    // ---------------- coalesced y2T store ----------------
    {
        u16* yb = y2T + ((size_t)b * HWN + rr * 256) * 256 + ci0;
#pragma unroll
        for (int j = 0; j < 16; ++j) {
            int c = (t >> 4) + (j << 4);
            int e = c * 128 + (((t & 15) ^ (t >> 4)) << 3);
            uint4 v = *(const uint4*)((char*)smem + (size_t)e * 2);
            *(uint4*)(yb + (size_t)c * 256 + (t & 15) * 8) = v;
        }
    }
}

extern "C" void kernel_launch(void* const* d_in, const int* in_sizes, int n_in,
                              void* d_out, int out_size, void* d_ws, size_t ws_size,
                              hipStream_t stream)
{
    const float* x       = (const float*)d_in[0];
    const float* phi_w   = (const float*)d_in[1];
    const float* phi_b   = (const float*)d_in[2];
    const float* theta_w = (const float*)d_in[3];
    const float* theta_b = (const float*)d_in[4];
    const float* gamma_w = (const float*)d_in[5];
    const float* gamma_b = (const float*)d_in[6];
    const float* W_w     = (const float*)d_in[7];
    const float* W_b     = (const float*)d_in[8];
    float* out = (float*)d_out;

    char* p = (char*)d_ws;
    u16* xT     = (u16*)p;  p += (size_t)NB * HWN * CIN * 2;   // 75.5 MB
    u16* phi_bf = (u16*)p;  p += (size_t)NB * OIN * HWN * 2;   // 37.7 MB
    u16* th_y2  = (u16*)p;  p += (size_t)NB * OIN * HWN * 2;   // 37.7 MB (theta, then y2T)
    float* xp   = (float*)p; p += (size_t)NB * CIN * KP * 4;
    u16* tpT    = (u16*)p;  p += (size_t)NB * 128 * 256 * 2;
    u16* gp     = (u16*)p;  p += (size_t)NB * 256 * 128 * 2;
    u16* Wcat   = (u16*)p;  p += 512 * 512 * 2;
    u16* Wwb    = (u16*)p;  p += 512 * 256 * 2;

    castw_kernel<<<1536, 256, 0, stream>>>(phi_w, theta_w, W_w, Wcat, Wwb);
    castx_kernel<<<dim3(144, 8, NB), 256, 0, stream>>>(x, xT);
    gemm_kernel<512, 0><<<dim3(72, 4, NB), 256, 0, stream>>>(
        xT, Wcat, phi_b, theta_b, nullptr, phi_bf, th_y2);
    pool_x_kernel<<<dim3(NB * CIN), 256, 0, stream>>>(x, xp);
    pool_t_kernel<<<dim3(NB * OIN), 256, 0, stream>>>(th_y2, tpT);
    gammap_kernel<<<dim3(128, NB), 256, 0, stream>>>(xp, gamma_w, gamma_b, gp);
    attn_kernel<<<dim3(72, NB), 256, 0, stream>>>(phi_bf, tpT, gp, th_y2);
    gemm_kernel<256, 1><<<dim3(72, 4, NB), 256, 0, stream>>>(
        th_y2, Wwb, W_b, nullptr, x, out, nullptr);
}